// Round 13
// baseline (481.635 us; speedup 1.0000x reference)
//
#include <hip/hip_runtime.h>
#include <cstdint>
#include <cstddef>

#define B_    4
#define S_    1024
#define CNN_DIM 512
#define LLM_DIM 768
#define BR_DIM  1024
#define NH    16
#define SAUG  1027

typedef __attribute__((ext_vector_type(8))) short short8;
typedef __attribute__((ext_vector_type(4))) float f32x4;
typedef __attribute__((ext_vector_type(4))) unsigned short us4;
typedef unsigned short u16;
typedef unsigned int u32;
typedef unsigned long long u64;

__device__ __forceinline__ float bf2f(u16 h) {
    union { u32 u; float f; } c; c.u = ((u32)h) << 16; return c.f;
}
__device__ __forceinline__ u16 f2bf(float f) {
    union { u32 u; float f; } c; c.f = f;
    return (u16)((c.u + 0x7FFFu + ((c.u >> 16) & 1u)) >> 16);
}
__device__ __forceinline__ short f2bfS(float f) { return (short)f2bf(f); }
__device__ __forceinline__ u32 cvt_pk_bf16(float lo, float hi) {
    u32 r;
    asm("v_cvt_pk_bf16_f32 %0, %1, %2" : "=v"(r) : "v"(lo), "v"(hi));
    return r;
}

#define GLLDS(gp, lp) __builtin_amdgcn_global_load_lds( \
    (const __attribute__((address_space(1))) void*)(gp), \
    (__attribute__((address_space(3))) void*)(lp), 16, 0, 0)

// ---------------- batched f32 -> bf16 conversion ----------------
#define NCONV 14
struct ConvArgs { const float* src[NCONV]; u16* dst[NCONV]; int cum[NCONV + 1]; };

__global__ __launch_bounds__(256) void convert_many(ConvArgs a, int total4) {
    int idx = blockIdx.x * 256 + threadIdx.x;
    if (idx >= total4) return;
    int seg = 0;
#pragma unroll
    for (int i = 1; i < NCONV; i++) if (a.cum[i] <= idx) seg = i;
    int j = idx - a.cum[seg];
    float4 v = ((const float4*)a.src[seg])[j];
    us4 o;
    o[0] = f2bf(v.x); o[1] = f2bf(v.y); o[2] = f2bf(v.z); o[3] = f2bf(v.w);
    ((us4*)a.dst[seg])[j] = o;
}

// ---------------- GEMM v2 (64x128 tile; M=4096-class shapes) ----------------
template<int RESID>   // 0 none, 1 bf16, 2 f32
__global__ __launch_bounds__(256) void gemm2_kernel(
    const u16* __restrict__ A, const u16* __restrict__ W,
    const float* __restrict__ bias, const void* __restrict__ residp,
    u16* __restrict__ C, int M, int N, int K)
{
    __shared__ u16 smA[2][64 * 64];
    __shared__ u16 smB[2][128 * 64];

    const int tid = threadIdx.x;
    const int lane = tid & 63;
    const int w = tid >> 6;
    const int wm = w & 1, wn = w >> 1;
    const int mi = lane & 15, g = lane >> 4;
    const int m0 = blockIdx.y * 64;
    const int n0 = blockIdx.x * 128;
    const int lrow = lane >> 3;
    const int lcol = lane & 7;

    f32x4 acc[2][4] = {};
    const int nk = K >> 6;
    int cur = 0;

    auto stage = [&](int buf, int kt) {
        const int kbase = kt * 64;
#pragma unroll
        for (int i = 0; i < 6; i++) {
            int c = w * 6 + i;
            if (c < 8) {
                int row = c * 8 + lrow;
                int col16 = lcol ^ (row & 7);
                int grow = m0 + row; if (grow > M - 1) grow = M - 1;
                GLLDS(A + (size_t)grow * K + kbase + col16 * 8, &smA[buf][c * 512]);
            } else {
                int c8 = c - 8;
                int row = c8 * 8 + lrow;
                int col16 = lcol ^ (row & 7);
                GLLDS(W + (size_t)(n0 + row) * K + kbase + col16 * 8, &smB[buf][c8 * 512]);
            }
        }
    };

    stage(0, 0);
    __syncthreads();

    for (int kt = 0; kt < nk; ++kt) {
        if (kt + 1 < nk) stage(cur ^ 1, kt + 1);
#pragma unroll
        for (int h = 0; h < 2; h++) {
            short8 af[2], bf[4];
#pragma unroll
            for (int im = 0; im < 2; im++) {
                int row = wm * 32 + im * 16 + mi;
                af[im] = *(const short8*)&smA[cur][row * 64 + ((h * 4 + g) ^ (mi & 7)) * 8];
            }
#pragma unroll
            for (int in = 0; in < 4; in++) {
                int row = wn * 64 + in * 16 + mi;
                bf[in] = *(const short8*)&smB[cur][row * 64 + ((h * 4 + g) ^ (mi & 7)) * 8];
            }
#pragma unroll
            for (int im = 0; im < 2; im++)
#pragma unroll
                for (int in = 0; in < 4; in++)
                    acc[im][in] = __builtin_amdgcn_mfma_f32_16x16x32_bf16(af[im], bf[in], acc[im][in], 0, 0, 0);
        }
        __syncthreads();
        cur ^= 1;
    }

#pragma unroll
    for (int im = 0; im < 2; im++) {
#pragma unroll
        for (int r = 0; r < 4; r++) {
            int row = m0 + wm * 32 + im * 16 + g * 4 + r;
            if (row >= M) continue;
            size_t base = (size_t)row * N;
#pragma unroll
            for (int in = 0; in < 4; in++) {
                int col = n0 + wn * 64 + in * 16 + mi;
                float v = acc[im][in][r] + bias[col];
                if (RESID == 1) v += bf2f(((const u16*)residp)[base + col]);
                if (RESID == 2) v += ((const float*)residp)[base + col];
                C[base + col] = f2bf(v);
            }
        }
    }
}

// ---------------- GEMM v3 (128x128 tile; M>=8192 shapes => ~2 blocks/CU) ----------------
template<int RESID>
__global__ __launch_bounds__(256) void gemm3_kernel(
    const u16* __restrict__ A, const u16* __restrict__ W,
    const float* __restrict__ bias, const void* __restrict__ residp,
    u16* __restrict__ C, int M, int N, int K)
{
    __shared__ u16 smA[2][128 * 64];
    __shared__ u16 smB[2][128 * 64];

    const int tid = threadIdx.x;
    const int lane = tid & 63;
    const int w = tid >> 6;
    const int wm = w & 1, wn = w >> 1;
    const int mi = lane & 15, g = lane >> 4;
    const int m0 = blockIdx.y * 128;
    const int n0 = blockIdx.x * 128;
    const int lrow = lane >> 3;
    const int lcol = lane & 7;

    f32x4 acc[4][4] = {};
    const int nk = K >> 6;
    int cur = 0;

    auto stage = [&](int buf, int kt) {
        const int kbase = kt * 64;
#pragma unroll
        for (int i = 0; i < 4; i++) {
            int c = w * 4 + i;
            int row = c * 8 + lrow;
            int col16 = lcol ^ (row & 7);
            int grow = m0 + row; if (grow > M - 1) grow = M - 1;
            GLLDS(A + (size_t)grow * K + kbase + col16 * 8, &smA[buf][c * 512]);
        }
#pragma unroll
        for (int i = 0; i < 4; i++) {
            int c = w * 4 + i;
            int row = c * 8 + lrow;
            int col16 = lcol ^ (row & 7);
            GLLDS(W + (size_t)(n0 + row) * K + kbase + col16 * 8, &smB[buf][c * 512]);
        }
    };

    stage(0, 0);
    __syncthreads();

    for (int kt = 0; kt < nk; ++kt) {
        if (kt + 1 < nk) stage(cur ^ 1, kt + 1);
#pragma unroll
        for (int h = 0; h < 2; h++) {
            short8 af[4], bf[4];
#pragma unroll
            for (int im = 0; im < 4; im++) {
                int row = wm * 64 + im * 16 + mi;
                af[im] = *(const short8*)&smA[cur][row * 64 + ((h * 4 + g) ^ (mi & 7)) * 8];
            }
#pragma unroll
            for (int in = 0; in < 4; in++) {
                int row = wn * 64 + in * 16 + mi;
                bf[in] = *(const short8*)&smB[cur][row * 64 + ((h * 4 + g) ^ (mi & 7)) * 8];
            }
#pragma unroll
            for (int im = 0; im < 4; im++)
#pragma unroll
                for (int in = 0; in < 4; in++)
                    acc[im][in] = __builtin_amdgcn_mfma_f32_16x16x32_bf16(af[im], bf[in], acc[im][in], 0, 0, 0);
        }
        __syncthreads();
        cur ^= 1;
    }

#pragma unroll
    for (int im = 0; im < 4; im++) {
#pragma unroll
        for (int r = 0; r < 4; r++) {
            int row = m0 + wm * 64 + im * 16 + g * 4 + r;
            if (row >= M) continue;
            size_t base = (size_t)row * N;
#pragma unroll
            for (int in = 0; in < 4; in++) {
                int col = n0 + wn * 64 + in * 16 + mi;
                float v = acc[im][in][r] + bias[col];
                if (RESID == 1) v += bf2f(((const u16*)residp)[base + col]);
                if (RESID == 2) v += ((const float*)residp)[base + col];
                C[base + col] = f2bf(v);
            }
        }
    }
}

// ---------------- V transpose: V[gb][key][h*DH+d] -> VT[gb][h][d][KPAD] (optional split halves) ----------------
template<int DH, bool SPLIT>
__global__ __launch_bounds__(256) void transpose_v(
    const u16* __restrict__ Vin, u16* __restrict__ VTa, u16* __restrict__ VTb,
    int Sk, int in_rs, long long in_bs, int KPAD)
{
    __shared__ u16 tile[64][DH + 8];
    const int tid = threadIdx.x;
    const int gb = blockIdx.z, h = blockIdx.y;
    const int k0 = blockIdx.x * 64;
    const u16* src = Vin + (size_t)gb * in_bs + h * DH;

    constexpr int CH = DH / 8;
    for (int i = tid; i < 64 * CH; i += 256) {
        int key = i / CH, c = i % CH;
        short8 v = {0,0,0,0,0,0,0,0};
        if (k0 + key < Sk) v = *(const short8*)(src + (size_t)(k0 + key) * in_rs + c * 8);
        *(short8*)&tile[key][c * 8] = v;
    }
    __syncthreads();

    u16* base;
    if (SPLIT) base = (gb < 4) ? (VTa + ((size_t)(gb * NH + h) * DH) * KPAD)
                               : (VTb + ((size_t)((gb - 4) * NH + h) * DH) * KPAD);
    else       base = VTa + ((size_t)(gb * NH + h) * DH) * KPAD;
    u16* dst = base + k0;
    for (int i = tid; i < DH * 8; i += 256) {
        int d = i >> 3, c = i & 7;
        short8 o;
#pragma unroll
        for (int j = 0; j < 8; j++) o[j] = (short)tile[c * 8 + j][d];
        *(short8*)(dst + (size_t)d * KPAD + c * 8) = o;
    }
}

// ---------------- MFMA flash attention v8: QG q-tiles/block, hoisted frags, no-max softmax ----------------
template<int DH, bool PHYS, int QG>
__global__ __launch_bounds__(256) void attn8(
    const u16* __restrict__ Q, const u16* __restrict__ Kb,
    const u16* __restrict__ VTa, const u16* __restrict__ VTb,
    u16* __restrict__ Ob, int Sk, int q_rs, int kv_rs, int o_rs,
    long long q_bs, long long kv_bs, long long o_bs, int KPAD, float scale)
{
    constexpr int KT = 32;
    constexpr int NDB = DH / 16;
    constexpr int NCH = DH / 32;
    constexpr int KLDP = DH + 8;
    constexpr int VLDP = 40;
    __shared__ __align__(16) u16 Kt[KT][KLDP];
    __shared__ __align__(16) u16 Vt[DH][VLDP];
    __shared__ __align__(16) u64 Px[4][16][10];

    const int tid = threadIdx.x;
    const int lane = tid & 63;
    const int w = tid >> 6;
    const int mi = lane & 15, g = lane >> 4;
    const int z = blockIdx.z, h = blockIdx.y;
    const int hoff = h * DH;
    const int qw = blockIdx.x * (64 * QG) + w * 16;
    const float sc2 = scale * 1.44269504088896f;

    int kb, vg;
    const u16* vts;
    if (PHYS) {
        kb = (z < 4) ? z + 4 : z - 4;
        vts = (z < 4) ? VTb : VTa;
        vg = (z < 4) ? z : z - 4;
    } else { kb = z; vts = VTa; vg = z; }

    int krow, kseg; bool kact;
    int vd, vks;   bool vact;
    if (DH == 64) { krow = tid >> 3; kseg = tid & 7; kact = true;
                    vd = tid >> 2;   vks = tid & 3;  vact = true; }
    else          { krow = tid >> 2; kseg = tid & 3; kact = (tid < 128);
                    vd = (tid - 128) >> 2; vks = tid & 3; vact = (tid >= 128); }

    short8 qfrag[QG][NCH];
#pragma unroll
    for (int qg = 0; qg < QG; qg++) {
        const u16* qs = Q + (size_t)z * q_bs + (size_t)(qw + qg * 64 + mi) * q_rs + hoff + g * 8;
#pragma unroll
        for (int c = 0; c < NCH; c++) {
            short8 q8 = *(const short8*)(qs + 32 * c);
#pragma unroll
            for (int j = 0; j < 8; j++) q8[j] = f2bfS(bf2f((u16)q8[j]) * sc2);
            qfrag[qg][c] = q8;
        }
    }

    const short one = (short)0x3F80;
    const short8 ones8 = {one, one, one, one, one, one, one, one};

    f32x4 acc[QG][NDB] = {};
    f32x4 accl[QG] = {};
    const u16* kbb = Kb + (size_t)kb * kv_bs + hoff;
    const u16* vtb = vts + ((size_t)(vg * NH + h) * DH) * KPAD;

    const int nt = (Sk + KT - 1) / KT;

    short8 kr8 = {0,0,0,0,0,0,0,0}, vr8 = {0,0,0,0,0,0,0,0};
    auto loadKV = [&](int t) {
        if (kact) {
            int key = t * KT + krow; if (key > Sk - 1) key = Sk - 1;
            kr8 = *(const short8*)(kbb + (size_t)key * kv_rs + kseg * 8);
        }
        if (vact)
            vr8 = *(const short8*)(vtb + (size_t)vd * KPAD + t * KT + vks * 8);
    };

    loadKV(0);

    for (int t = 0; t < nt; t++) {
        const int rem = Sk - t * KT;
        __syncthreads();
        if (kact) *(short8*)&Kt[krow][kseg * 8] = kr8;
        if (vact) *(short8*)&Vt[vd][vks * 8] = vr8;
        __syncthreads();
        if (t + 1 < nt) loadKV(t + 1);

        // ---- hoisted K and V fragments (shared across q-groups) ----
        short8 ka[NCH], kb8[NCH], vf[NDB];
#pragma unroll
        for (int c = 0; c < NCH; c++) {
            ka[c]  = *(const short8*)&Kt[mi][g * 8 + 32 * c];
            kb8[c] = *(const short8*)&Kt[16 + mi][g * 8 + 32 * c];
        }
#pragma unroll
        for (int db = 0; db < NDB; db++)
            vf[db] = *(const short8*)&Vt[db * 16 + mi][g * 8];

#pragma unroll
        for (int qg = 0; qg < QG; qg++) {
            // ---- QK^T ----
            f32x4 sA = {0,0,0,0}, sB = {0,0,0,0};
#pragma unroll
            for (int c = 0; c < NCH; c++) {
                sA = __builtin_amdgcn_mfma_f32_16x16x32_bf16(ka[c],  qfrag[qg][c], sA, 0, 0, 0);
                sB = __builtin_amdgcn_mfma_f32_16x16x32_bf16(kb8[c], qfrag[qg][c], sB, 0, 0, 0);
            }

            // ---- no-max softmax terms ----
            float pa[4], pb[4];
            if (rem >= KT) {
#pragma unroll
                for (int r = 0; r < 4; r++) {
                    pa[r] = exp2f(sA[r]);
                    pb[r] = exp2f(sB[r]);
                }
            } else {
#pragma unroll
                for (int r = 0; r < 4; r++) {
                    pa[r] = (4 * g + r < rem)      ? exp2f(sA[r]) : 0.f;
                    pb[r] = (16 + 4 * g + r < rem) ? exp2f(sB[r]) : 0.f;
                }
            }

            // ---- P exchange (wave-internal LDS, sequential reuse across qg) ----
            {
                uint2 wa, wb;
                wa.x = cvt_pk_bf16(pa[0], pa[1]);
                wa.y = cvt_pk_bf16(pa[2], pa[3]);
                wb.x = cvt_pk_bf16(pb[0], pb[1]);
                wb.y = cvt_pk_bf16(pb[2], pb[3]);
                uint2* prow = (uint2*)&Px[w][mi][0];
                prow[g] = wa;
                prow[4 + g] = wb;
            }
            short8 pfrag = *(const short8*)((const u16*)&Px[w][mi][0] + 8 * g);

            // ---- denominator + PV ----
            accl[qg] = __builtin_amdgcn_mfma_f32_16x16x32_bf16(ones8, pfrag, accl[qg], 0, 0, 0);
#pragma unroll
            for (int db = 0; db < NDB; db++)
                acc[qg][db] = __builtin_amdgcn_mfma_f32_16x16x32_bf16(vf[db], pfrag, acc[qg][db], 0, 0, 0);
        }
    }

#pragma unroll
    for (int qg = 0; qg < QG; qg++) {
        const float inv = 1.f / accl[qg][0];
        u16* obase = Ob + (size_t)z * o_bs + (size_t)(qw + qg * 64 + mi) * o_rs + hoff;
#pragma unroll
        for (int db = 0; db < NDB; db++)
#pragma unroll
            for (int r = 0; r < 4; r++)
                obase[db * 16 + 4 * g + r] = f2bf(acc[qg][db][r] * inv);
    }
}

// ---------------- LayerNorm (vectorized) ----------------
template<bool GELU, bool RESID, bool OUTF32>
__global__ __launch_bounds__(256) void ln_kernel(
    const u16* __restrict__ X, const u16* __restrict__ resid,
    const float* __restrict__ gg, const float* __restrict__ be,
    void* __restrict__ out, int N, int rows_per_batch,
    long long resid_bs, int resid_rs, long long out_bs, int out_rs)
{
    __shared__ float buf[1024];
    __shared__ float red[2][4];
    __shared__ float stat[2];
    const int row = blockIdx.x;
    const int b = row / rows_per_batch, r = row % rows_per_batch;
    const int tid = threadIdx.x, lane = tid & 63, w = tid >> 6;
    const u16* xr = X + (size_t)row * N;
    const u16* rr = RESID ? (resid + (size_t)b * resid_bs + (size_t)r * resid_rs) : (const u16*)nullptr;

    float s = 0.f, s2 = 0.f;
    for (int i0 = tid * 4; i0 < N; i0 += 1024) {
        us4 xv = *(const us4*)(xr + i0);
        us4 rv = {0,0,0,0};
        if (RESID) rv = *(const us4*)(rr + i0);
        float4 xb;
        float* xp = &xb.x;
#pragma unroll
        for (int u = 0; u < 4; u++) {
            float x = bf2f(xv[u]);
            if (RESID) x += bf2f(rv[u]);
            if (GELU)  x = 0.5f * x * (1.f + erff(x * 0.70710678118654752f));
            xp[u] = x; s += x; s2 += x * x;
        }
        *(float4*)&buf[i0] = xb;
    }
#pragma unroll
    for (int off = 32; off; off >>= 1) { s += __shfl_xor(s, off); s2 += __shfl_xor(s2, off); }
    if (lane == 0) { red[0][w] = s; red[1][w] = s2; }
    __syncthreads();
    if (tid == 0) {
        float a = red[0][0] + red[0][1] + red[0][2] + red[0][3];
        float q = red[1][0] + red[1][1] + red[1][2] + red[1][3];
        float mean = a / N;
        float var = q / N - mean * mean;
        stat[0] = mean; stat[1] = rsqrtf(var + 1e-5f);
    }
    __syncthreads();
    const float mean = stat[0], rs = stat[1];
    const size_t obase = (size_t)b * out_bs + (size_t)r * out_rs;
    for (int i0 = tid * 4; i0 < N; i0 += 1024) {
        if (OUTF32) {
            float4 o;
            o.x = (buf[i0+0] - mean) * rs * gg[i0+0] + be[i0+0];
            o.y = (buf[i0+1] - mean) * rs * gg[i0+1] + be[i0+1];
            o.z = (buf[i0+2] - mean) * rs * gg[i0+2] + be[i0+2];
            o.w = (buf[i0+3] - mean) * rs * gg[i0+3] + be[i0+3];
            *(float4*)((float*)out + obase + i0) = o;
        } else {
            us4 o;
#pragma unroll
            for (int u = 0; u < 4; u++)
                o[u] = f2bf((buf[i0+u] - mean) * rs * gg[i0+u] + be[i0+u]);
            *(us4*)((u16*)out + obase + i0) = o;
        }
    }
}

// ---------------- phys embedding rows (f32 src -> bf16) ----------------
__global__ __launch_bounds__(256) void fill_phys_kernel(
    const float* __restrict__ e, const float* __restrict__ m, const float* __restrict__ p,
    u16* __restrict__ augc, u16* __restrict__ augl)
{
    int i = blockIdx.x * 256 + threadIdx.x;
    if (i >= 3 * BR_DIM) return;
    int r = i / BR_DIM, j = i % BR_DIM;
    u16 v = f2bf((r == 0) ? e[j] : (r == 1) ? m[j] : p[j]);
#pragma unroll
    for (int b = 0; b < B_; b++) {
        size_t off = ((size_t)b * SAUG + S_ + r) * BR_DIM + j;
        augc[off] = v; augl[off] = v;
    }
}

template<int RESID>
static void gemm(hipStream_t s, const u16* A, const u16* W, const float* bias,
                 const void* resid, u16* C, int M, int N, int K)
{
    if (M >= 8192) {
        dim3 grid(N / 128, (M + 127) / 128), block(256);
        gemm3_kernel<RESID><<<grid, block, 0, s>>>(A, W, bias, resid, C, M, N, K);
    } else {
        dim3 grid(N / 128, (M + 63) / 64), block(256);
        gemm2_kernel<RESID><<<grid, block, 0, s>>>(A, W, bias, resid, C, M, N, K);
    }
}

extern "C" void kernel_launch(void* const* d_in, const int* in_sizes, int n_in,
                              void* d_out, int out_size, void* d_ws, size_t ws_size,
                              hipStream_t stream)
{
    auto F = [&](int i) { return (const float*)d_in[i]; };
    uint8_t* ws = (uint8_t*)d_ws;

    // ---- workspace layout (high-water ~99.1 MB; ws>=112MB evidenced by r2/r3 bit-identity) ----
    u16* W_SA_QKV = (u16*)(ws + 256);
    u16* W_SA_O   = (u16*)(ws + 1573120);
    u16* W_TA_QKV = (u16*)(ws + 2097408);
    u16* W_TA_O   = (u16*)(ws + 3670272);
    u16* W_C2B    = (u16*)(ws + 4194560);
    u16* W_L2B    = (u16*)(ws + 5243136);
    u16* W_PQ     = (u16*)(ws + 6816000);
    u16* W_PK     = (u16*)(ws + 8913152);
    u16* W_PV     = (u16*)(ws + 11010304);
    u16* W_PO     = (u16*)(ws + 13107456);
    u16* W_C2L    = (u16*)(ws + 15204608);
    u16* W_L2C    = (u16*)(ws + 16777472);
    u16* VT32     = (u16*)(ws + 17826048);   // 4 MB (MHA V^T; CNN_B region)
    u16* CNN_B    = (u16*)(ws + 17826048);   // dead after MHA1 QKV gemm
    u16* LLM_B    = (u16*)(ws + 22020352);   // dead after l2b gemm
    u16* QKV      = (u16*)(ws + 28311808);   // 12.6 MB; X8 bridge scratch alias
    u16* ATT      = (u16*)(ws + 40894720);   // 4 MB
    u16* CNN1     = (u16*)(ws + 45089024);
    u16* CNN2     = (u16*)(ws + 49283328);
    u16* AUGC     = (u16*)(ws + 53477632);   // 8 batches contiguous w/ AUGL
    u16* AUGL     = (u16*)(ws + 61890816);
    u16* VTA      = (u16*)(ws + 17826048);   // 8.9 MB (phys V^T groups 0-3)
    u16* PV_ALL   = (u16*)(ws + 26738944);   // 16.8 MB, end 43565312
    u16* VTB      = (u16*)(ws + 43565312);   // 8.9 MB, end 52478208
    u16* OB_ALL   = (u16*)(ws + 26738944);   // over dead PV_ALL
    u16* PQ_ALL   = (u16*)(ws + 70304000);   // 16.8 MB
    u16* PK_ALL   = (u16*)(ws + 87130368);   // 16.8 MB, end 103956736
    u16* X8       = QKV;                     // bridge scratch (8 MB)
    u16* X8_ALL   = (u16*)(ws + 70304000);   // PO out, over dead PQ_ALL
    u16* CATT_ALL = (u16*)(ws + 87130368);   // over dead PK_ALL, 16.8 MB
    u16* X6       = (u16*)(ws + 26738944);   // over dead OB_ALL
    u16* X4       = (u16*)(ws + 26738944);
    float* outp   = (float*)d_out;

    // ---- convert weights + features to bf16 ----
    ConvArgs ca;
    const float* srcs[NCONV] = { F(1), F(2), F(3), F(5), F(7), F(9), F(11),
                                 F(15), F(19), F(21), F(23), F(25), F(32), F(36) };
    u16* dsts[NCONV] = { LLM_B, CNN_B, W_SA_QKV, W_SA_O, W_TA_QKV, W_TA_O, W_C2B,
                         W_L2B, W_PQ, W_PK, W_PV, W_PO, W_C2L, W_L2C };
    const int ns[NCONV] = { 3145728, 2097152, 786432, 262144, 786432, 262144, 524288,
                            786432, 1048576, 1048576, 1048576, 1048576, 786432, 524288 };
    int cum = 0;
    for (int i = 0; i < NCONV; i++) { ca.src[i] = srcs[i]; ca.dst[i] = dsts[i]; ca.cum[i] = cum; cum += ns[i] / 4; }
    ca.cum[NCONV] = cum;
    convert_many<<<(cum + 255) / 256, 256, 0, stream>>>(ca, cum);

    const int M4 = B_ * S_;
    const int MA = B_ * SAUG;
    const float sc32 = 0.17677669529663687f;
    const float sc64 = 0.125f;
    const long long bsQKV = (long long)S_ * 3 * CNN_DIM;
    const long long bsATT = (long long)S_ * CNN_DIM;
    const long long bsAUG = (long long)SAUG * BR_DIM;
    const long long bsO   = (long long)S_ * BR_DIM;
    const int KP32 = 1024;
    const int KP64 = 1088;
    dim3 ablock(256);
    dim3 agrid4(S_ / 128, NH, B_), agrid8(S_ / 128, NH, 2 * B_);
    dim3 tgrid32(16, NH, B_), tgrid64(17, NH, 2 * B_);

    // ---- MHA 1 (spatial) ----
    gemm<0>(stream, CNN_B, W_SA_QKV, F(4), nullptr, QKV, M4, 3 * CNN_DIM, CNN_DIM);
    transpose_v<32, false><<<tgrid32, 256, 0, stream>>>(QKV + 2 * CNN_DIM, VT32, nullptr, S_, 3 * CNN_DIM, bsQKV, KP32);
    attn8<32, false, 2><<<agrid4, ablock, 0, stream>>>(QKV, QKV + CNN_DIM, VT32, nullptr, ATT,
        S_, 3 * CNN_DIM, 3 * CNN_DIM, CNN_DIM, bsQKV, bsQKV, bsATT, KP32, sc32);
    gemm<2>(stream, ATT, W_SA_O, F(6), F(2), CNN1, M4, CNN_DIM, CNN_DIM);

    // ---- MHA 2 (temporal) ----
    gemm<0>(stream, CNN1, W_TA_QKV, F(8), nullptr, QKV, M4, 3 * CNN_DIM, CNN_DIM);
    transpose_v<32, false><<<tgrid32, 256, 0, stream>>>(QKV + 2 * CNN_DIM, VT32, nullptr, S_, 3 * CNN_DIM, bsQKV, KP32);
    attn8<32, false, 2><<<agrid4, ablock, 0, stream>>>(QKV, QKV + CNN_DIM, VT32, nullptr, ATT,
        S_, 3 * CNN_DIM, 3 * CNN_DIM, CNN_DIM, bsQKV, bsQKV, bsATT, KP32, sc32);
    gemm<1>(stream, ATT, W_TA_O, F(10), CNN1, CNN2, M4, CNN_DIM, CNN_DIM);

    // ---- bridges to BR_DIM (Linear -> GELU -> LN) ----
    gemm<0>(stream, LLM_B, W_L2B, F(16), nullptr, X8, M4, BR_DIM, LLM_DIM);
    ln_kernel<true, false, false><<<M4, 256, 0, stream>>>(X8, nullptr, F(17), F(18), AUGL,
        BR_DIM, S_, 0, 0, bsAUG, BR_DIM);
    gemm<0>(stream, CNN2, W_C2B, F(12), nullptr, X8, M4, BR_DIM, CNN_DIM);
    ln_kernel<true, false, false><<<M4, 256, 0, stream>>>(X8, nullptr, F(13), F(14), AUGC,
        BR_DIM, S_, 0, 0, bsAUG, BR_DIM);
    fill_phys_kernel<<<12, 256, 0, stream>>>(F(27), F(28), F(29), AUGC, AUGL);

    // ---- merged phys projections over [AUGC;AUGL] (M = 8216, gemm3) ----
    gemm<0>(stream, AUGC, W_PQ, F(20), nullptr, PQ_ALL, 2 * MA, BR_DIM, BR_DIM);
    gemm<0>(stream, AUGC, W_PK, F(22), nullptr, PK_ALL, 2 * MA, BR_DIM, BR_DIM);
    gemm<0>(stream, AUGC, W_PV, F(24), nullptr, PV_ALL, 2 * MA, BR_DIM, BR_DIM);
    transpose_v<64, true><<<tgrid64, 256, 0, stream>>>(PV_ALL, VTA, VTB, SAUG, BR_DIM, bsAUG, KP64);

    // ---- merged phys attention (z<4: cnn-q x llm-kv; z>=4: llm-q x cnn-kv) ----
    attn8<64, true, 2><<<agrid8, ablock, 0, stream>>>(PQ_ALL, PK_ALL, VTA, VTB, OB_ALL,
        SAUG, BR_DIM, BR_DIM, BR_DIM, bsAUG, bsAUG, bsO, KP64, sc64);

    // ---- merged PO projection (M=8192, gemm3) + residual LN ----
    gemm<0>(stream, OB_ALL, W_PO, F(26), nullptr, X8_ALL, 2 * M4, BR_DIM, BR_DIM);
    ln_kernel<false, true, false><<<2 * M4, 256, 0, stream>>>(X8_ALL, AUGC, F(30), F(31), CATT_ALL,
        BR_DIM, S_, bsAUG, BR_DIM, bsO, BR_DIM);

    // ---- final bridges (f32 to d_out) ----
    gemm<0>(stream, CATT_ALL, W_C2L, F(33), nullptr, X6, M4, LLM_DIM, BR_DIM);
    ln_kernel<true, false, true><<<M4, 256, 0, stream>>>(X6, nullptr, F(34), F(35),
        (void*)(outp + 2097152), LLM_DIM, S_, 0, 0, (long long)S_ * LLM_DIM, LLM_DIM);
    gemm<0>(stream, CATT_ALL + (size_t)M4 * BR_DIM, W_L2C, F(37), nullptr, X4, M4, CNN_DIM, BR_DIM);
    ln_kernel<true, false, true><<<M4, 256, 0, stream>>>(X4, nullptr, F(38), F(39),
        (void*)outp, CNN_DIM, S_, 0, 0, (long long)S_ * CNN_DIM, CNN_DIM);
}

// Round 14
// 459.553 us; speedup vs baseline: 1.0481x; 1.0481x over previous
//
#include <hip/hip_runtime.h>
#include <cstdint>
#include <cstddef>

#define B_    4
#define S_    1024
#define CNN_DIM 512
#define LLM_DIM 768
#define BR_DIM  1024
#define NH    16
#define SAUG  1027

typedef __attribute__((ext_vector_type(8))) short short8;
typedef __attribute__((ext_vector_type(4))) float f32x4;
typedef __attribute__((ext_vector_type(4))) unsigned short us4;
typedef unsigned short u16;
typedef unsigned int u32;
typedef unsigned long long u64;

__device__ __forceinline__ float bf2f(u16 h) {
    union { u32 u; float f; } c; c.u = ((u32)h) << 16; return c.f;
}
__device__ __forceinline__ u16 f2bf(float f) {
    union { u32 u; float f; } c; c.f = f;
    return (u16)((c.u + 0x7FFFu + ((c.u >> 16) & 1u)) >> 16);
}
__device__ __forceinline__ short f2bfS(float f) { return (short)f2bf(f); }
__device__ __forceinline__ u32 cvt_pk_bf16(float lo, float hi) {
    u32 r;
    asm("v_cvt_pk_bf16_f32 %0, %1, %2" : "=v"(r) : "v"(lo), "v"(hi));
    return r;
}

#define GLLDS(gp, lp) __builtin_amdgcn_global_load_lds( \
    (const __attribute__((address_space(1))) void*)(gp), \
    (__attribute__((address_space(3))) void*)(lp), 16, 0, 0)

// ---------------- batched f32 -> bf16 conversion ----------------
#define NCONV 14
struct ConvArgs { const float* src[NCONV]; u16* dst[NCONV]; int cum[NCONV + 1]; };

__global__ __launch_bounds__(256) void convert_many(ConvArgs a, int total4) {
    int idx = blockIdx.x * 256 + threadIdx.x;
    if (idx >= total4) return;
    int seg = 0;
#pragma unroll
    for (int i = 1; i < NCONV; i++) if (a.cum[i] <= idx) seg = i;
    int j = idx - a.cum[seg];
    float4 v = ((const float4*)a.src[seg])[j];
    us4 o;
    o[0] = f2bf(v.x); o[1] = f2bf(v.y); o[2] = f2bf(v.z); o[3] = f2bf(v.w);
    ((us4*)a.dst[seg])[j] = o;
}

// ---------------- fused bias for PQ|PK ----------------
__global__ __launch_bounds__(256) void fill_bias2(
    const float* __restrict__ b0, const float* __restrict__ b1, float* __restrict__ out)
{
    int i = blockIdx.x * 256 + threadIdx.x;
    if (i < 1024) out[i] = b0[i];
    else if (i < 2048) out[i] = b1[i - 1024];
}

// ---------------- GEMM v2 (64x128 tile) ----------------
template<int RESID>   // 0 none, 1 bf16, 2 f32
__global__ __launch_bounds__(256) void gemm2_kernel(
    const u16* __restrict__ A, const u16* __restrict__ W,
    const float* __restrict__ bias, const void* __restrict__ residp,
    u16* __restrict__ C, int M, int N, int K)
{
    __shared__ u16 smA[2][64 * 64];
    __shared__ u16 smB[2][128 * 64];

    const int tid = threadIdx.x;
    const int lane = tid & 63;
    const int w = tid >> 6;
    const int wm = w & 1, wn = w >> 1;
    const int mi = lane & 15, g = lane >> 4;
    const int m0 = blockIdx.y * 64;
    const int n0 = blockIdx.x * 128;
    const int lrow = lane >> 3;
    const int lcol = lane & 7;

    f32x4 acc[2][4] = {};
    const int nk = K >> 6;
    int cur = 0;

    auto stage = [&](int buf, int kt) {
        const int kbase = kt * 64;
#pragma unroll
        for (int i = 0; i < 6; i++) {
            int c = w * 6 + i;
            if (c < 8) {
                int row = c * 8 + lrow;
                int col16 = lcol ^ (row & 7);
                int grow = m0 + row; if (grow > M - 1) grow = M - 1;
                GLLDS(A + (size_t)grow * K + kbase + col16 * 8, &smA[buf][c * 512]);
            } else {
                int c8 = c - 8;
                int row = c8 * 8 + lrow;
                int col16 = lcol ^ (row & 7);
                GLLDS(W + (size_t)(n0 + row) * K + kbase + col16 * 8, &smB[buf][c8 * 512]);
            }
        }
    };

    stage(0, 0);
    __syncthreads();

    for (int kt = 0; kt < nk; ++kt) {
        if (kt + 1 < nk) stage(cur ^ 1, kt + 1);
#pragma unroll
        for (int h = 0; h < 2; h++) {
            short8 af[2], bf[4];
#pragma unroll
            for (int im = 0; im < 2; im++) {
                int row = wm * 32 + im * 16 + mi;
                af[im] = *(const short8*)&smA[cur][row * 64 + ((h * 4 + g) ^ (mi & 7)) * 8];
            }
#pragma unroll
            for (int in = 0; in < 4; in++) {
                int row = wn * 64 + in * 16 + mi;
                bf[in] = *(const short8*)&smB[cur][row * 64 + ((h * 4 + g) ^ (mi & 7)) * 8];
            }
#pragma unroll
            for (int im = 0; im < 2; im++)
#pragma unroll
                for (int in = 0; in < 4; in++)
                    acc[im][in] = __builtin_amdgcn_mfma_f32_16x16x32_bf16(af[im], bf[in], acc[im][in], 0, 0, 0);
        }
        __syncthreads();
        cur ^= 1;
    }

#pragma unroll
    for (int im = 0; im < 2; im++) {
#pragma unroll
        for (int r = 0; r < 4; r++) {
            int row = m0 + wm * 32 + im * 16 + g * 4 + r;
            if (row >= M) continue;
            size_t base = (size_t)row * N;
#pragma unroll
            for (int in = 0; in < 4; in++) {
                int col = n0 + wn * 64 + in * 16 + mi;
                float v = acc[im][in][r] + bias[col];
                if (RESID == 1) v += bf2f(((const u16*)residp)[base + col]);
                if (RESID == 2) v += ((const float*)residp)[base + col];
                C[base + col] = f2bf(v);
            }
        }
    }
}

// ---------------- V transpose: V[gb][key][h*DH+d] -> VT[gb][h][d][KPAD] (optional split halves) ----------------
template<int DH, bool SPLIT>
__global__ __launch_bounds__(256) void transpose_v(
    const u16* __restrict__ Vin, u16* __restrict__ VTa, u16* __restrict__ VTb,
    int Sk, int in_rs, long long in_bs, int KPAD)
{
    __shared__ u16 tile[64][DH + 8];
    const int tid = threadIdx.x;
    const int gb = blockIdx.z, h = blockIdx.y;
    const int k0 = blockIdx.x * 64;
    const u16* src = Vin + (size_t)gb * in_bs + h * DH;

    constexpr int CH = DH / 8;
    for (int i = tid; i < 64 * CH; i += 256) {
        int key = i / CH, c = i % CH;
        short8 v = {0,0,0,0,0,0,0,0};
        if (k0 + key < Sk) v = *(const short8*)(src + (size_t)(k0 + key) * in_rs + c * 8);
        *(short8*)&tile[key][c * 8] = v;
    }
    __syncthreads();

    u16* base;
    if (SPLIT) base = (gb < 4) ? (VTa + ((size_t)(gb * NH + h) * DH) * KPAD)
                               : (VTb + ((size_t)((gb - 4) * NH + h) * DH) * KPAD);
    else       base = VTa + ((size_t)(gb * NH + h) * DH) * KPAD;
    u16* dst = base + k0;
    for (int i = tid; i < DH * 8; i += 256) {
        int d = i >> 3, c = i & 7;
        short8 o;
#pragma unroll
        for (int j = 0; j < 8; j++) o[j] = (short)tile[c * 8 + j][d];
        *(short8*)(dst + (size_t)d * KPAD + c * 8) = o;
    }
}

// ---------------- MFMA flash attention v8: QG q-tiles/block, hoisted frags, no-max softmax ----------------
template<int DH, bool PHYS, int QG>
__global__ __launch_bounds__(256) void attn8(
    const u16* __restrict__ Q, const u16* __restrict__ Kb,
    const u16* __restrict__ VTa, const u16* __restrict__ VTb,
    u16* __restrict__ Ob, int Sk, int q_rs, int kv_rs, int o_rs,
    long long q_bs, long long kv_bs, long long o_bs, int KPAD, float scale)
{
    constexpr int KT = 32;
    constexpr int NDB = DH / 16;
    constexpr int NCH = DH / 32;
    constexpr int KLDP = DH + 8;
    constexpr int VLDP = 40;
    __shared__ __align__(16) u16 Kt[KT][KLDP];
    __shared__ __align__(16) u16 Vt[DH][VLDP];
    __shared__ __align__(16) u64 Px[4][16][10];

    const int tid = threadIdx.x;
    const int lane = tid & 63;
    const int w = tid >> 6;
    const int mi = lane & 15, g = lane >> 4;
    const int z = blockIdx.z, h = blockIdx.y;
    const int hoff = h * DH;
    const int qw = blockIdx.x * (64 * QG) + w * 16;
    const float sc2 = scale * 1.44269504088896f;

    int kb, vg;
    const u16* vts;
    if (PHYS) {
        kb = (z < 4) ? z + 4 : z - 4;
        vts = (z < 4) ? VTb : VTa;
        vg = (z < 4) ? z : z - 4;
    } else { kb = z; vts = VTa; vg = z; }

    int krow, kseg; bool kact;
    int vd, vks;   bool vact;
    if (DH == 64) { krow = tid >> 3; kseg = tid & 7; kact = true;
                    vd = tid >> 2;   vks = tid & 3;  vact = true; }
    else          { krow = tid >> 2; kseg = tid & 3; kact = (tid < 128);
                    vd = (tid - 128) >> 2; vks = tid & 3; vact = (tid >= 128); }

    short8 qfrag[QG][NCH];
#pragma unroll
    for (int qg = 0; qg < QG; qg++) {
        const u16* qs = Q + (size_t)z * q_bs + (size_t)(qw + qg * 64 + mi) * q_rs + hoff + g * 8;
#pragma unroll
        for (int c = 0; c < NCH; c++) {
            short8 q8 = *(const short8*)(qs + 32 * c);
#pragma unroll
            for (int j = 0; j < 8; j++) q8[j] = f2bfS(bf2f((u16)q8[j]) * sc2);
            qfrag[qg][c] = q8;
        }
    }

    const short one = (short)0x3F80;
    const short8 ones8 = {one, one, one, one, one, one, one, one};

    f32x4 acc[QG][NDB] = {};
    f32x4 accl[QG] = {};
    const u16* kbb = Kb + (size_t)kb * kv_bs + hoff;
    const u16* vtb = vts + ((size_t)(vg * NH + h) * DH) * KPAD;

    const int nt = (Sk + KT - 1) / KT;

    short8 kr8 = {0,0,0,0,0,0,0,0}, vr8 = {0,0,0,0,0,0,0,0};
    auto loadKV = [&](int t) {
        if (kact) {
            int key = t * KT + krow; if (key > Sk - 1) key = Sk - 1;
            kr8 = *(const short8*)(kbb + (size_t)key * kv_rs + kseg * 8);
        }
        if (vact)
            vr8 = *(const short8*)(vtb + (size_t)vd * KPAD + t * KT + vks * 8);
    };

    loadKV(0);

    for (int t = 0; t < nt; t++) {
        const int rem = Sk - t * KT;
        __syncthreads();
        if (kact) *(short8*)&Kt[krow][kseg * 8] = kr8;
        if (vact) *(short8*)&Vt[vd][vks * 8] = vr8;
        __syncthreads();
        if (t + 1 < nt) loadKV(t + 1);

        // ---- hoisted K and V fragments (shared across q-groups) ----
        short8 ka[NCH], kb8[NCH], vf[NDB];
#pragma unroll
        for (int c = 0; c < NCH; c++) {
            ka[c]  = *(const short8*)&Kt[mi][g * 8 + 32 * c];
            kb8[c] = *(const short8*)&Kt[16 + mi][g * 8 + 32 * c];
        }
#pragma unroll
        for (int db = 0; db < NDB; db++)
            vf[db] = *(const short8*)&Vt[db * 16 + mi][g * 8];

#pragma unroll
        for (int qg = 0; qg < QG; qg++) {
            // ---- QK^T ----
            f32x4 sA = {0,0,0,0}, sB = {0,0,0,0};
#pragma unroll
            for (int c = 0; c < NCH; c++) {
                sA = __builtin_amdgcn_mfma_f32_16x16x32_bf16(ka[c],  qfrag[qg][c], sA, 0, 0, 0);
                sB = __builtin_amdgcn_mfma_f32_16x16x32_bf16(kb8[c], qfrag[qg][c], sB, 0, 0, 0);
            }

            // ---- no-max softmax terms ----
            float pa[4], pb[4];
            if (rem >= KT) {
#pragma unroll
                for (int r = 0; r < 4; r++) {
                    pa[r] = exp2f(sA[r]);
                    pb[r] = exp2f(sB[r]);
                }
            } else {
#pragma unroll
                for (int r = 0; r < 4; r++) {
                    pa[r] = (4 * g + r < rem)      ? exp2f(sA[r]) : 0.f;
                    pb[r] = (16 + 4 * g + r < rem) ? exp2f(sB[r]) : 0.f;
                }
            }

            // ---- P exchange (wave-internal LDS, sequential reuse across qg) ----
            {
                uint2 wa, wb;
                wa.x = cvt_pk_bf16(pa[0], pa[1]);
                wa.y = cvt_pk_bf16(pa[2], pa[3]);
                wb.x = cvt_pk_bf16(pb[0], pb[1]);
                wb.y = cvt_pk_bf16(pb[2], pb[3]);
                uint2* prow = (uint2*)&Px[w][mi][0];
                prow[g] = wa;
                prow[4 + g] = wb;
            }
            short8 pfrag = *(const short8*)((const u16*)&Px[w][mi][0] + 8 * g);

            // ---- denominator + PV ----
            accl[qg] = __builtin_amdgcn_mfma_f32_16x16x32_bf16(ones8, pfrag, accl[qg], 0, 0, 0);
#pragma unroll
            for (int db = 0; db < NDB; db++)
                acc[qg][db] = __builtin_amdgcn_mfma_f32_16x16x32_bf16(vf[db], pfrag, acc[qg][db], 0, 0, 0);
        }
    }

#pragma unroll
    for (int qg = 0; qg < QG; qg++) {
        const float inv = 1.f / accl[qg][0];
        u16* obase = Ob + (size_t)z * o_bs + (size_t)(qw + qg * 64 + mi) * o_rs + hoff;
#pragma unroll
        for (int db = 0; db < NDB; db++)
#pragma unroll
            for (int r = 0; r < 4; r++)
                obase[db * 16 + 4 * g + r] = f2bf(acc[qg][db][r] * inv);
    }
}

// ---------------- LayerNorm (vectorized) ----------------
template<bool GELU, bool RESID, bool OUTF32>
__global__ __launch_bounds__(256) void ln_kernel(
    const u16* __restrict__ X, const u16* __restrict__ resid,
    const float* __restrict__ gg, const float* __restrict__ be,
    void* __restrict__ out, int N, int rows_per_batch,
    long long resid_bs, int resid_rs, long long out_bs, int out_rs)
{
    __shared__ float buf[1024];
    __shared__ float red[2][4];
    __shared__ float stat[2];
    const int row = blockIdx.x;
    const int b = row / rows_per_batch, r = row % rows_per_batch;
    const int tid = threadIdx.x, lane = tid & 63, w = tid >> 6;
    const u16* xr = X + (size_t)row * N;
    const u16* rr = RESID ? (resid + (size_t)b * resid_bs + (size_t)r * resid_rs) : (const u16*)nullptr;

    float s = 0.f, s2 = 0.f;
    for (int i0 = tid * 4; i0 < N; i0 += 1024) {
        us4 xv = *(const us4*)(xr + i0);
        us4 rv = {0,0,0,0};
        if (RESID) rv = *(const us4*)(rr + i0);
        float4 xb;
        float* xp = &xb.x;
#pragma unroll
        for (int u = 0; u < 4; u++) {
            float x = bf2f(xv[u]);
            if (RESID) x += bf2f(rv[u]);
            if (GELU)  x = 0.5f * x * (1.f + erff(x * 0.70710678118654752f));
            xp[u] = x; s += x; s2 += x * x;
        }
        *(float4*)&buf[i0] = xb;
    }
#pragma unroll
    for (int off = 32; off; off >>= 1) { s += __shfl_xor(s, off); s2 += __shfl_xor(s2, off); }
    if (lane == 0) { red[0][w] = s; red[1][w] = s2; }
    __syncthreads();
    if (tid == 0) {
        float a = red[0][0] + red[0][1] + red[0][2] + red[0][3];
        float q = red[1][0] + red[1][1] + red[1][2] + red[1][3];
        float mean = a / N;
        float var = q / N - mean * mean;
        stat[0] = mean; stat[1] = rsqrtf(var + 1e-5f);
    }
    __syncthreads();
    const float mean = stat[0], rs = stat[1];
    const size_t obase = (size_t)b * out_bs + (size_t)r * out_rs;
    for (int i0 = tid * 4; i0 < N; i0 += 1024) {
        if (OUTF32) {
            float4 o;
            o.x = (buf[i0+0] - mean) * rs * gg[i0+0] + be[i0+0];
            o.y = (buf[i0+1] - mean) * rs * gg[i0+1] + be[i0+1];
            o.z = (buf[i0+2] - mean) * rs * gg[i0+2] + be[i0+2];
            o.w = (buf[i0+3] - mean) * rs * gg[i0+3] + be[i0+3];
            *(float4*)((float*)out + obase + i0) = o;
        } else {
            us4 o;
#pragma unroll
            for (int u = 0; u < 4; u++)
                o[u] = f2bf((buf[i0+u] - mean) * rs * gg[i0+u] + be[i0+u]);
            *(us4*)((u16*)out + obase + i0) = o;
        }
    }
}

// ---------------- phys embedding rows (f32 src -> bf16) ----------------
__global__ __launch_bounds__(256) void fill_phys_kernel(
    const float* __restrict__ e, const float* __restrict__ m, const float* __restrict__ p,
    u16* __restrict__ augc, u16* __restrict__ augl)
{
    int i = blockIdx.x * 256 + threadIdx.x;
    if (i >= 3 * BR_DIM) return;
    int r = i / BR_DIM, j = i % BR_DIM;
    u16 v = f2bf((r == 0) ? e[j] : (r == 1) ? m[j] : p[j]);
#pragma unroll
    for (int b = 0; b < B_; b++) {
        size_t off = ((size_t)b * SAUG + S_ + r) * BR_DIM + j;
        augc[off] = v; augl[off] = v;
    }
}

template<int RESID>
static void gemm(hipStream_t s, const u16* A, const u16* W, const float* bias,
                 const void* resid, u16* C, int M, int N, int K)
{
    dim3 grid(N / 128, (M + 63) / 64), block(256);
    gemm2_kernel<RESID><<<grid, block, 0, s>>>(A, W, bias, resid, C, M, N, K);
}

extern "C" void kernel_launch(void* const* d_in, const int* in_sizes, int n_in,
                              void* d_out, int out_size, void* d_ws, size_t ws_size,
                              hipStream_t stream)
{
    auto F = [&](int i) { return (const float*)d_in[i]; };
    uint8_t* ws = (uint8_t*)d_ws;

    // ---- workspace layout (high-water 103,956,736 B; proven by rounds 12/13) ----
    u16* W_SA_QKV = (u16*)(ws + 256);
    u16* W_SA_O   = (u16*)(ws + 1573120);
    u16* W_TA_QKV = (u16*)(ws + 2097408);
    u16* W_TA_O   = (u16*)(ws + 3670272);
    u16* W_C2B    = (u16*)(ws + 4194560);
    u16* W_L2B    = (u16*)(ws + 5243136);
    u16* W_PQ     = (u16*)(ws + 6816000);   // W_PQ|W_PK|W_PV contiguous => fused [3072][1024]
    u16* W_PK     = (u16*)(ws + 8913152);
    u16* W_PV     = (u16*)(ws + 11010304);
    u16* W_PO     = (u16*)(ws + 13107456);
    u16* W_C2L    = (u16*)(ws + 15204608);
    u16* W_L2C    = (u16*)(ws + 16777472);
    u16* VT32     = (u16*)(ws + 17826048);   // 4 MB (MHA V^T; CNN_B region)
    u16* CNN_B    = (u16*)(ws + 17826048);   // dead after MHA1 QKV gemm
    u16* LLM_B    = (u16*)(ws + 22020352);   // dead after l2b gemm
    u16* QKV      = (u16*)(ws + 28311808);   // 12.6 MB; X8 bridge scratch alias
    u16* ATT      = (u16*)(ws + 40894720);   // 4 MB
    u16* CNN1     = (u16*)(ws + 45089024);
    u16* CNN2     = (u16*)(ws + 49283328);
    u16* AUGC     = (u16*)(ws + 53477632);   // 8 batches contiguous w/ AUGL
    u16* AUGL     = (u16*)(ws + 61890816);   // end 70,304,000
    u16* VTA      = (u16*)(ws + 17826048);   // 8.9 MB (phys V^T groups 0-3; over dead CNN_B/LLM_B)
    u16* PV_ALL   = (u16*)(ws + 26738944);   // 16.8 MB, end 43,565,312 (over dead QKV/ATT)
    u16* VTB      = (u16*)(ws + 43565312);   // 8.9 MB, end 52,478,208
    float* BIAS2  = (float*)(ws + 52478208); // 8 KB fused PQ|PK bias
    u16* OB_ALL   = (u16*)(ws + 26738944);   // over dead PV_ALL
    u16* PQK_ALL  = (u16*)(ws + 70304000);   // [8216][2048] = 33.65 MB, end 103,956,736
    u16* X8       = QKV;                     // bridge scratch (8 MB)
    u16* X8_ALL   = (u16*)(ws + 70304000);   // PO out, over dead PQK_ALL
    u16* CATT_ALL = (u16*)(ws + 87130368);   // 16.8 MB, end 103,956,736
    u16* X6       = (u16*)(ws + 26738944);   // over dead OB_ALL
    u16* X4       = (u16*)(ws + 26738944);
    float* outp   = (float*)d_out;

    // ---- convert weights + features to bf16 ----
    ConvArgs ca;
    const float* srcs[NCONV] = { F(1), F(2), F(3), F(5), F(7), F(9), F(11),
                                 F(15), F(19), F(21), F(23), F(25), F(32), F(36) };
    u16* dsts[NCONV] = { LLM_B, CNN_B, W_SA_QKV, W_SA_O, W_TA_QKV, W_TA_O, W_C2B,
                         W_L2B, W_PQ, W_PK, W_PV, W_PO, W_C2L, W_L2C };
    const int ns[NCONV] = { 3145728, 2097152, 786432, 262144, 786432, 262144, 524288,
                            786432, 1048576, 1048576, 1048576, 1048576, 786432, 524288 };
    int cum = 0;
    for (int i = 0; i < NCONV; i++) { ca.src[i] = srcs[i]; ca.dst[i] = dsts[i]; ca.cum[i] = cum; cum += ns[i] / 4; }
    ca.cum[NCONV] = cum;
    convert_many<<<(cum + 255) / 256, 256, 0, stream>>>(ca, cum);
    fill_bias2<<<8, 256, 0, stream>>>(F(20), F(22), BIAS2);

    const int M4 = B_ * S_;
    const int MA = B_ * SAUG;
    const float sc32 = 0.17677669529663687f;
    const float sc64 = 0.125f;
    const long long bsQKV = (long long)S_ * 3 * CNN_DIM;
    const long long bsATT = (long long)S_ * CNN_DIM;
    const long long bsAUG = (long long)SAUG * BR_DIM;
    const long long bsPQK = (long long)SAUG * 2048;
    const long long bsO   = (long long)S_ * BR_DIM;
    const int KP32 = 1024;
    const int KP64 = 1088;
    dim3 ablock(256);
    dim3 agrid4(S_ / 128, NH, B_), agrid8(S_ / 256, NH, 2 * B_);
    dim3 tgrid32(16, NH, B_), tgrid64(17, NH, 2 * B_);

    // ---- MHA 1 (spatial) ----
    gemm<0>(stream, CNN_B, W_SA_QKV, F(4), nullptr, QKV, M4, 3 * CNN_DIM, CNN_DIM);
    transpose_v<32, false><<<tgrid32, 256, 0, stream>>>(QKV + 2 * CNN_DIM, VT32, nullptr, S_, 3 * CNN_DIM, bsQKV, KP32);
    attn8<32, false, 2><<<agrid4, ablock, 0, stream>>>(QKV, QKV + CNN_DIM, VT32, nullptr, ATT,
        S_, 3 * CNN_DIM, 3 * CNN_DIM, CNN_DIM, bsQKV, bsQKV, bsATT, KP32, sc32);
    gemm<2>(stream, ATT, W_SA_O, F(6), F(2), CNN1, M4, CNN_DIM, CNN_DIM);

    // ---- MHA 2 (temporal) ----
    gemm<0>(stream, CNN1, W_TA_QKV, F(8), nullptr, QKV, M4, 3 * CNN_DIM, CNN_DIM);
    transpose_v<32, false><<<tgrid32, 256, 0, stream>>>(QKV + 2 * CNN_DIM, VT32, nullptr, S_, 3 * CNN_DIM, bsQKV, KP32);
    attn8<32, false, 2><<<agrid4, ablock, 0, stream>>>(QKV, QKV + CNN_DIM, VT32, nullptr, ATT,
        S_, 3 * CNN_DIM, 3 * CNN_DIM, CNN_DIM, bsQKV, bsQKV, bsATT, KP32, sc32);
    gemm<1>(stream, ATT, W_TA_O, F(10), CNN1, CNN2, M4, CNN_DIM, CNN_DIM);

    // ---- bridges to BR_DIM (Linear -> GELU -> LN) ----
    gemm<0>(stream, LLM_B, W_L2B, F(16), nullptr, X8, M4, BR_DIM, LLM_DIM);
    ln_kernel<true, false, false><<<M4, 256, 0, stream>>>(X8, nullptr, F(17), F(18), AUGL,
        BR_DIM, S_, 0, 0, bsAUG, BR_DIM);
    gemm<0>(stream, CNN2, W_C2B, F(12), nullptr, X8, M4, BR_DIM, CNN_DIM);
    ln_kernel<true, false, false><<<M4, 256, 0, stream>>>(X8, nullptr, F(13), F(14), AUGC,
        BR_DIM, S_, 0, 0, bsAUG, BR_DIM);
    fill_phys_kernel<<<12, 256, 0, stream>>>(F(27), F(28), F(29), AUGC, AUGL);

    // ---- merged phys projections: fused Q|K (N=2048) + V, over [AUGC;AUGL] (M=8216) ----
    gemm<0>(stream, AUGC, W_PQ, BIAS2, nullptr, PQK_ALL, 2 * MA, 2048, BR_DIM);
    gemm<0>(stream, AUGC, W_PV, F(24), nullptr, PV_ALL, 2 * MA, BR_DIM, BR_DIM);
    transpose_v<64, true><<<tgrid64, 256, 0, stream>>>(PV_ALL, VTA, VTB, SAUG, BR_DIM, bsAUG, KP64);

    // ---- merged phys attention, QG=4 (z<4: cnn-q x llm-kv; z>=4: llm-q x cnn-kv) ----
    attn8<64, true, 4><<<agrid8, ablock, 0, stream>>>(PQK_ALL, PQK_ALL + 1024, VTA, VTB, OB_ALL,
        SAUG, 2048, 2048, BR_DIM, bsPQK, bsPQK, bsO, KP64, sc64);

    // ---- merged PO projection + residual LN ----
    gemm<0>(stream, OB_ALL, W_PO, F(26), nullptr, X8_ALL, 2 * M4, BR_DIM, BR_DIM);
    ln_kernel<false, true, false><<<2 * M4, 256, 0, stream>>>(X8_ALL, AUGC, F(30), F(31), CATT_ALL,
        BR_DIM, S_, bsAUG, BR_DIM, bsO, BR_DIM);

    // ---- final bridges (f32 to d_out) ----
    gemm<0>(stream, CATT_ALL, W_C2L, F(33), nullptr, X6, M4, LLM_DIM, BR_DIM);
    ln_kernel<true, false, true><<<M4, 256, 0, stream>>>(X6, nullptr, F(34), F(35),
        (void*)(outp + 2097152), LLM_DIM, S_, 0, 0, (long long)S_ * LLM_DIM, LLM_DIM);
    gemm<0>(stream, CATT_ALL + (size_t)M4 * BR_DIM, W_L2C, F(37), nullptr, X4, M4, CNN_DIM, BR_DIM);
    ln_kernel<true, false, true><<<M4, 256, 0, stream>>>(X4, nullptr, F(38), F(39),
        (void*)outp, CNN_DIM, S_, 0, 0, (long long)S_ * CNN_DIM, CNN_DIM);
}

// Round 15
// 457.936 us; speedup vs baseline: 1.0518x; 1.0035x over previous
//
#include <hip/hip_runtime.h>
#include <cstdint>
#include <cstddef>

#define B_    4
#define S_    1024
#define CNN_DIM 512
#define LLM_DIM 768
#define BR_DIM  1024
#define NH    16
#define SAUG  1027

typedef __attribute__((ext_vector_type(8))) short short8;
typedef __attribute__((ext_vector_type(4))) float f32x4;
typedef __attribute__((ext_vector_type(4))) unsigned short us4;
typedef unsigned short u16;
typedef unsigned int u32;
typedef unsigned long long u64;

__device__ __forceinline__ float bf2f(u16 h) {
    union { u32 u; float f; } c; c.u = ((u32)h) << 16; return c.f;
}
__device__ __forceinline__ u16 f2bf(float f) {
    union { u32 u; float f; } c; c.f = f;
    return (u16)((c.u + 0x7FFFu + ((c.u >> 16) & 1u)) >> 16);
}
__device__ __forceinline__ short f2bfS(float f) { return (short)f2bf(f); }
__device__ __forceinline__ u32 cvt_pk_bf16(float lo, float hi) {
    u32 r;
    asm("v_cvt_pk_bf16_f32 %0, %1, %2" : "=v"(r) : "v"(lo), "v"(hi));
    return r;
}

#define GLLDS(gp, lp) __builtin_amdgcn_global_load_lds( \
    (const __attribute__((address_space(1))) void*)(gp), \
    (__attribute__((address_space(3))) void*)(lp), 16, 0, 0)

// ---------------- batched f32 -> bf16 conversion ----------------
#define NCONV 14
struct ConvArgs { const float* src[NCONV]; u16* dst[NCONV]; int cum[NCONV + 1]; };

__global__ __launch_bounds__(256) void convert_many(ConvArgs a, int total4) {
    int idx = blockIdx.x * 256 + threadIdx.x;
    if (idx >= total4) return;
    int seg = 0;
#pragma unroll
    for (int i = 1; i < NCONV; i++) if (a.cum[i] <= idx) seg = i;
    int j = idx - a.cum[seg];
    float4 v = ((const float4*)a.src[seg])[j];
    us4 o;
    o[0] = f2bf(v.x); o[1] = f2bf(v.y); o[2] = f2bf(v.z); o[3] = f2bf(v.w);
    ((us4*)a.dst[seg])[j] = o;
}

// ---------------- fused bias for PQ|PK ----------------
__global__ __launch_bounds__(256) void fill_bias2(
    const float* __restrict__ b0, const float* __restrict__ b1, float* __restrict__ out)
{
    int i = blockIdx.x * 256 + threadIdx.x;
    if (i < 1024) out[i] = b0[i];
    else if (i < 2048) out[i] = b1[i - 1024];
}

// ---------------- GEMM v2 (64x128 tile) ----------------
template<int RESID>   // 0 none, 1 bf16, 2 f32
__global__ __launch_bounds__(256) void gemm2_kernel(
    const u16* __restrict__ A, const u16* __restrict__ W,
    const float* __restrict__ bias, const void* __restrict__ residp,
    u16* __restrict__ C, int M, int N, int K)
{
    __shared__ u16 smA[2][64 * 64];
    __shared__ u16 smB[2][128 * 64];

    const int tid = threadIdx.x;
    const int lane = tid & 63;
    const int w = tid >> 6;
    const int wm = w & 1, wn = w >> 1;
    const int mi = lane & 15, g = lane >> 4;
    const int m0 = blockIdx.y * 64;
    const int n0 = blockIdx.x * 128;
    const int lrow = lane >> 3;
    const int lcol = lane & 7;

    f32x4 acc[2][4] = {};
    const int nk = K >> 6;
    int cur = 0;

    auto stage = [&](int buf, int kt) {
        const int kbase = kt * 64;
#pragma unroll
        for (int i = 0; i < 6; i++) {
            int c = w * 6 + i;
            if (c < 8) {
                int row = c * 8 + lrow;
                int col16 = lcol ^ (row & 7);
                int grow = m0 + row; if (grow > M - 1) grow = M - 1;
                GLLDS(A + (size_t)grow * K + kbase + col16 * 8, &smA[buf][c * 512]);
            } else {
                int c8 = c - 8;
                int row = c8 * 8 + lrow;
                int col16 = lcol ^ (row & 7);
                GLLDS(W + (size_t)(n0 + row) * K + kbase + col16 * 8, &smB[buf][c8 * 512]);
            }
        }
    };

    stage(0, 0);
    __syncthreads();

    for (int kt = 0; kt < nk; ++kt) {
        if (kt + 1 < nk) stage(cur ^ 1, kt + 1);
#pragma unroll
        for (int h = 0; h < 2; h++) {
            short8 af[2], bf[4];
#pragma unroll
            for (int im = 0; im < 2; im++) {
                int row = wm * 32 + im * 16 + mi;
                af[im] = *(const short8*)&smA[cur][row * 64 + ((h * 4 + g) ^ (mi & 7)) * 8];
            }
#pragma unroll
            for (int in = 0; in < 4; in++) {
                int row = wn * 64 + in * 16 + mi;
                bf[in] = *(const short8*)&smB[cur][row * 64 + ((h * 4 + g) ^ (mi & 7)) * 8];
            }
#pragma unroll
            for (int im = 0; im < 2; im++)
#pragma unroll
                for (int in = 0; in < 4; in++)
                    acc[im][in] = __builtin_amdgcn_mfma_f32_16x16x32_bf16(af[im], bf[in], acc[im][in], 0, 0, 0);
        }
        __syncthreads();
        cur ^= 1;
    }

#pragma unroll
    for (int im = 0; im < 2; im++) {
#pragma unroll
        for (int r = 0; r < 4; r++) {
            int row = m0 + wm * 32 + im * 16 + g * 4 + r;
            if (row >= M) continue;
            size_t base = (size_t)row * N;
#pragma unroll
            for (int in = 0; in < 4; in++) {
                int col = n0 + wn * 64 + in * 16 + mi;
                float v = acc[im][in][r] + bias[col];
                if (RESID == 1) v += bf2f(((const u16*)residp)[base + col]);
                if (RESID == 2) v += ((const float*)residp)[base + col];
                C[base + col] = f2bf(v);
            }
        }
    }
}

// ---------------- V transpose: V[gb][key][h*DH+d] -> VT[gb][h][d][KPAD] (optional split halves) ----------------
template<int DH, bool SPLIT>
__global__ __launch_bounds__(256) void transpose_v(
    const u16* __restrict__ Vin, u16* __restrict__ VTa, u16* __restrict__ VTb,
    int Sk, int in_rs, long long in_bs, int KPAD)
{
    __shared__ u16 tile[64][DH + 8];
    const int tid = threadIdx.x;
    const int gb = blockIdx.z, h = blockIdx.y;
    const int k0 = blockIdx.x * 64;
    const u16* src = Vin + (size_t)gb * in_bs + h * DH;

    constexpr int CH = DH / 8;
    for (int i = tid; i < 64 * CH; i += 256) {
        int key = i / CH, c = i % CH;
        short8 v = {0,0,0,0,0,0,0,0};
        if (k0 + key < Sk) v = *(const short8*)(src + (size_t)(k0 + key) * in_rs + c * 8);
        *(short8*)&tile[key][c * 8] = v;
    }
    __syncthreads();

    u16* base;
    if (SPLIT) base = (gb < 4) ? (VTa + ((size_t)(gb * NH + h) * DH) * KPAD)
                               : (VTb + ((size_t)((gb - 4) * NH + h) * DH) * KPAD);
    else       base = VTa + ((size_t)(gb * NH + h) * DH) * KPAD;
    u16* dst = base + k0;
    for (int i = tid; i < DH * 8; i += 256) {
        int d = i >> 3, c = i & 7;
        short8 o;
#pragma unroll
        for (int j = 0; j < 8; j++) o[j] = (short)tile[c * 8 + j][d];
        *(short8*)(dst + (size_t)d * KPAD + c * 8) = o;
    }
}

// ---------------- MFMA flash attention v9: double-buffered LDS, 1 barrier/tile ----------------
template<int DH, bool PHYS, int QG>
__global__ __launch_bounds__(256) void attn9(
    const u16* __restrict__ Q, const u16* __restrict__ Kb,
    const u16* __restrict__ VTa, const u16* __restrict__ VTb,
    u16* __restrict__ Ob, int Sk, int q_rs, int kv_rs, int o_rs,
    long long q_bs, long long kv_bs, long long o_bs, int KPAD, float scale)
{
    constexpr int KT = 32;
    constexpr int NDB = DH / 16;
    constexpr int NCH = DH / 32;
    constexpr int KLDP = DH + 8;
    constexpr int VLDP = 40;
    __shared__ __align__(16) u16 Kt[2][KT][KLDP];
    __shared__ __align__(16) u16 Vt[2][DH][VLDP];
    __shared__ __align__(16) u64 Px[4][16][10];

    const int tid = threadIdx.x;
    const int lane = tid & 63;
    const int w = tid >> 6;
    const int mi = lane & 15, g = lane >> 4;
    const int z = blockIdx.z, h = blockIdx.y;
    const int hoff = h * DH;
    const int qw = blockIdx.x * (64 * QG) + w * 16;
    const float sc2 = scale * 1.44269504088896f;

    int kb, vg;
    const u16* vts;
    if (PHYS) {
        kb = (z < 4) ? z + 4 : z - 4;
        vts = (z < 4) ? VTb : VTa;
        vg = (z < 4) ? z : z - 4;
    } else { kb = z; vts = VTa; vg = z; }

    int krow, kseg; bool kact;
    int vd, vks;   bool vact;
    if (DH == 64) { krow = tid >> 3; kseg = tid & 7; kact = true;
                    vd = tid >> 2;   vks = tid & 3;  vact = true; }
    else          { krow = tid >> 2; kseg = tid & 3; kact = (tid < 128);
                    vd = (tid - 128) >> 2; vks = tid & 3; vact = (tid >= 128); }

    short8 qfrag[QG][NCH];
#pragma unroll
    for (int qg = 0; qg < QG; qg++) {
        const u16* qs = Q + (size_t)z * q_bs + (size_t)(qw + qg * 64 + mi) * q_rs + hoff + g * 8;
#pragma unroll
        for (int c = 0; c < NCH; c++) {
            short8 q8 = *(const short8*)(qs + 32 * c);
#pragma unroll
            for (int j = 0; j < 8; j++) q8[j] = f2bfS(bf2f((u16)q8[j]) * sc2);
            qfrag[qg][c] = q8;
        }
    }

    const short one = (short)0x3F80;
    const short8 ones8 = {one, one, one, one, one, one, one, one};

    f32x4 acc[QG][NDB] = {};
    f32x4 accl[QG] = {};
    const u16* kbb = Kb + (size_t)kb * kv_bs + hoff;
    const u16* vtb = vts + ((size_t)(vg * NH + h) * DH) * KPAD;

    const int nt = (Sk + KT - 1) / KT;

    short8 kr8 = {0,0,0,0,0,0,0,0}, vr8 = {0,0,0,0,0,0,0,0};
    auto loadKV = [&](int t) {
        if (kact) {
            int key = t * KT + krow; if (key > Sk - 1) key = Sk - 1;
            kr8 = *(const short8*)(kbb + (size_t)key * kv_rs + kseg * 8);
        }
        if (vact)
            vr8 = *(const short8*)(vtb + (size_t)vd * KPAD + t * KT + vks * 8);
    };

    // prologue: tile 0 -> LDS[0]; prefetch tile 1 into regs
    loadKV(0);
    if (kact) *(short8*)&Kt[0][krow][kseg * 8] = kr8;
    if (vact) *(short8*)&Vt[0][vd][vks * 8] = vr8;
    if (nt > 1) loadKV(1);
    __syncthreads();

    for (int t = 0; t < nt; t++) {
        const int rem = Sk - t * KT;
        const int cur = t & 1;
        // write tile t+1 into the other buffer (its last readers finished at t-1,
        // separated by the barrier at end of t-1); prefetch tile t+2 into regs
        if (t + 1 < nt) {
            const int nb = cur ^ 1;
            if (kact) *(short8*)&Kt[nb][krow][kseg * 8] = kr8;
            if (vact) *(short8*)&Vt[nb][vd][vks * 8] = vr8;
            if (t + 2 < nt) loadKV(t + 2);
        }

        // ---- hoisted K and V fragments (shared across q-groups) ----
        short8 ka[NCH], kb8[NCH], vf[NDB];
#pragma unroll
        for (int c = 0; c < NCH; c++) {
            ka[c]  = *(const short8*)&Kt[cur][mi][g * 8 + 32 * c];
            kb8[c] = *(const short8*)&Kt[cur][16 + mi][g * 8 + 32 * c];
        }
#pragma unroll
        for (int db = 0; db < NDB; db++)
            vf[db] = *(const short8*)&Vt[cur][db * 16 + mi][g * 8];

#pragma unroll
        for (int qg = 0; qg < QG; qg++) {
            // ---- QK^T ----
            f32x4 sA = {0,0,0,0}, sB = {0,0,0,0};
#pragma unroll
            for (int c = 0; c < NCH; c++) {
                sA = __builtin_amdgcn_mfma_f32_16x16x32_bf16(ka[c],  qfrag[qg][c], sA, 0, 0, 0);
                sB = __builtin_amdgcn_mfma_f32_16x16x32_bf16(kb8[c], qfrag[qg][c], sB, 0, 0, 0);
            }

            // ---- no-max softmax terms ----
            float pa[4], pb[4];
            if (rem >= KT) {
#pragma unroll
                for (int r = 0; r < 4; r++) {
                    pa[r] = exp2f(sA[r]);
                    pb[r] = exp2f(sB[r]);
                }
            } else {
#pragma unroll
                for (int r = 0; r < 4; r++) {
                    pa[r] = (4 * g + r < rem)      ? exp2f(sA[r]) : 0.f;
                    pb[r] = (16 + 4 * g + r < rem) ? exp2f(sB[r]) : 0.f;
                }
            }

            // ---- P exchange (wave-internal LDS) ----
            {
                uint2 wa, wb;
                wa.x = cvt_pk_bf16(pa[0], pa[1]);
                wa.y = cvt_pk_bf16(pa[2], pa[3]);
                wb.x = cvt_pk_bf16(pb[0], pb[1]);
                wb.y = cvt_pk_bf16(pb[2], pb[3]);
                uint2* prow = (uint2*)&Px[w][mi][0];
                prow[g] = wa;
                prow[4 + g] = wb;
            }
            short8 pfrag = *(const short8*)((const u16*)&Px[w][mi][0] + 8 * g);

            // ---- denominator + PV ----
            accl[qg] = __builtin_amdgcn_mfma_f32_16x16x32_bf16(ones8, pfrag, accl[qg], 0, 0, 0);
#pragma unroll
            for (int db = 0; db < NDB; db++)
                acc[qg][db] = __builtin_amdgcn_mfma_f32_16x16x32_bf16(vf[db], pfrag, acc[qg][db], 0, 0, 0);
        }
        __syncthreads();   // single barrier per tile
    }

#pragma unroll
    for (int qg = 0; qg < QG; qg++) {
        const float inv = 1.f / accl[qg][0];
        u16* obase = Ob + (size_t)z * o_bs + (size_t)(qw + qg * 64 + mi) * o_rs + hoff;
#pragma unroll
        for (int db = 0; db < NDB; db++)
#pragma unroll
            for (int r = 0; r < 4; r++)
                obase[db * 16 + 4 * g + r] = f2bf(acc[qg][db][r] * inv);
    }
}

// ---------------- LayerNorm (vectorized) ----------------
template<bool GELU, bool RESID, bool OUTF32>
__global__ __launch_bounds__(256) void ln_kernel(
    const u16* __restrict__ X, const u16* __restrict__ resid,
    const float* __restrict__ gg, const float* __restrict__ be,
    void* __restrict__ out, int N, int rows_per_batch,
    long long resid_bs, int resid_rs, long long out_bs, int out_rs)
{
    __shared__ float buf[1024];
    __shared__ float red[2][4];
    __shared__ float stat[2];
    const int row = blockIdx.x;
    const int b = row / rows_per_batch, r = row % rows_per_batch;
    const int tid = threadIdx.x, lane = tid & 63, w = tid >> 6;
    const u16* xr = X + (size_t)row * N;
    const u16* rr = RESID ? (resid + (size_t)b * resid_bs + (size_t)r * resid_rs) : (const u16*)nullptr;

    float s = 0.f, s2 = 0.f;
    for (int i0 = tid * 4; i0 < N; i0 += 1024) {
        us4 xv = *(const us4*)(xr + i0);
        us4 rv = {0,0,0,0};
        if (RESID) rv = *(const us4*)(rr + i0);
        float4 xb;
        float* xp = &xb.x;
#pragma unroll
        for (int u = 0; u < 4; u++) {
            float x = bf2f(xv[u]);
            if (RESID) x += bf2f(rv[u]);
            if (GELU)  x = 0.5f * x * (1.f + erff(x * 0.70710678118654752f));
            xp[u] = x; s += x; s2 += x * x;
        }
        *(float4*)&buf[i0] = xb;
    }
#pragma unroll
    for (int off = 32; off; off >>= 1) { s += __shfl_xor(s, off); s2 += __shfl_xor(s2, off); }
    if (lane == 0) { red[0][w] = s; red[1][w] = s2; }
    __syncthreads();
    if (tid == 0) {
        float a = red[0][0] + red[0][1] + red[0][2] + red[0][3];
        float q = red[1][0] + red[1][1] + red[1][2] + red[1][3];
        float mean = a / N;
        float var = q / N - mean * mean;
        stat[0] = mean; stat[1] = rsqrtf(var + 1e-5f);
    }
    __syncthreads();
    const float mean = stat[0], rs = stat[1];
    const size_t obase = (size_t)b * out_bs + (size_t)r * out_rs;
    for (int i0 = tid * 4; i0 < N; i0 += 1024) {
        if (OUTF32) {
            float4 o;
            o.x = (buf[i0+0] - mean) * rs * gg[i0+0] + be[i0+0];
            o.y = (buf[i0+1] - mean) * rs * gg[i0+1] + be[i0+1];
            o.z = (buf[i0+2] - mean) * rs * gg[i0+2] + be[i0+2];
            o.w = (buf[i0+3] - mean) * rs * gg[i0+3] + be[i0+3];
            *(float4*)((float*)out + obase + i0) = o;
        } else {
            us4 o;
#pragma unroll
            for (int u = 0; u < 4; u++)
                o[u] = f2bf((buf[i0+u] - mean) * rs * gg[i0+u] + be[i0+u]);
            *(us4*)((u16*)out + obase + i0) = o;
        }
    }
}

// ---------------- phys embedding rows (f32 src -> bf16) ----------------
__global__ __launch_bounds__(256) void fill_phys_kernel(
    const float* __restrict__ e, const float* __restrict__ m, const float* __restrict__ p,
    u16* __restrict__ augc, u16* __restrict__ augl)
{
    int i = blockIdx.x * 256 + threadIdx.x;
    if (i >= 3 * BR_DIM) return;
    int r = i / BR_DIM, j = i % BR_DIM;
    u16 v = f2bf((r == 0) ? e[j] : (r == 1) ? m[j] : p[j]);
#pragma unroll
    for (int b = 0; b < B_; b++) {
        size_t off = ((size_t)b * SAUG + S_ + r) * BR_DIM + j;
        augc[off] = v; augl[off] = v;
    }
}

template<int RESID>
static void gemm(hipStream_t s, const u16* A, const u16* W, const float* bias,
                 const void* resid, u16* C, int M, int N, int K)
{
    dim3 grid(N / 128, (M + 63) / 64), block(256);
    gemm2_kernel<RESID><<<grid, block, 0, s>>>(A, W, bias, resid, C, M, N, K);
}

extern "C" void kernel_launch(void* const* d_in, const int* in_sizes, int n_in,
                              void* d_out, int out_size, void* d_ws, size_t ws_size,
                              hipStream_t stream)
{
    auto F = [&](int i) { return (const float*)d_in[i]; };
    uint8_t* ws = (uint8_t*)d_ws;

    // ---- workspace layout (high-water 103,956,736 B; proven rounds 12-14) ----
    u16* W_SA_QKV = (u16*)(ws + 256);
    u16* W_SA_O   = (u16*)(ws + 1573120);
    u16* W_TA_QKV = (u16*)(ws + 2097408);
    u16* W_TA_O   = (u16*)(ws + 3670272);
    u16* W_C2B    = (u16*)(ws + 4194560);
    u16* W_L2B    = (u16*)(ws + 5243136);
    u16* W_PQ     = (u16*)(ws + 6816000);   // W_PQ|W_PK contiguous => fused [2048][1024]
    u16* W_PK     = (u16*)(ws + 8913152);
    u16* W_PV     = (u16*)(ws + 11010304);
    u16* W_PO     = (u16*)(ws + 13107456);
    u16* W_C2L    = (u16*)(ws + 15204608);
    u16* W_L2C    = (u16*)(ws + 16777472);
    u16* VT32     = (u16*)(ws + 17826048);   // 4 MB (MHA V^T; CNN_B region)
    u16* CNN_B    = (u16*)(ws + 17826048);   // dead after MHA1 QKV gemm
    u16* LLM_B    = (u16*)(ws + 22020352);   // dead after l2b gemm
    u16* QKV      = (u16*)(ws + 28311808);   // 12.6 MB; X8 bridge scratch alias
    u16* ATT      = (u16*)(ws + 40894720);   // 4 MB
    u16* CNN1     = (u16*)(ws + 45089024);
    u16* CNN2     = (u16*)(ws + 49283328);
    u16* AUGC     = (u16*)(ws + 53477632);   // 8 batches contiguous w/ AUGL
    u16* AUGL     = (u16*)(ws + 61890816);   // end 70,304,000
    u16* VTA      = (u16*)(ws + 17826048);   // 8.9 MB (phys V^T groups 0-3; over dead CNN_B/LLM_B)
    u16* PV_ALL   = (u16*)(ws + 26738944);   // 16.8 MB, end 43,565,312 (over dead QKV/ATT)
    u16* VTB      = (u16*)(ws + 43565312);   // 8.9 MB, end 52,478,208
    float* BIAS2  = (float*)(ws + 52478208); // 8 KB fused PQ|PK bias
    u16* OB_ALL   = (u16*)(ws + 26738944);   // over dead PV_ALL
    u16* PQK_ALL  = (u16*)(ws + 70304000);   // [8216][2048] = 33.65 MB, end 103,956,736
    u16* X8       = QKV;                     // bridge scratch (8 MB)
    u16* X8_ALL   = (u16*)(ws + 70304000);   // PO out, over dead PQK_ALL
    u16* CATT_ALL = (u16*)(ws + 87130368);   // 16.8 MB, end 103,956,736
    u16* X6       = (u16*)(ws + 26738944);   // over dead OB_ALL
    u16* X4       = (u16*)(ws + 26738944);
    float* outp   = (float*)d_out;

    // ---- convert weights + features to bf16 ----
    ConvArgs ca;
    const float* srcs[NCONV] = { F(1), F(2), F(3), F(5), F(7), F(9), F(11),
                                 F(15), F(19), F(21), F(23), F(25), F(32), F(36) };
    u16* dsts[NCONV] = { LLM_B, CNN_B, W_SA_QKV, W_SA_O, W_TA_QKV, W_TA_O, W_C2B,
                         W_L2B, W_PQ, W_PK, W_PV, W_PO, W_C2L, W_L2C };
    const int ns[NCONV] = { 3145728, 2097152, 786432, 262144, 786432, 262144, 524288,
                            786432, 1048576, 1048576, 1048576, 1048576, 786432, 524288 };
    int cum = 0;
    for (int i = 0; i < NCONV; i++) { ca.src[i] = srcs[i]; ca.dst[i] = dsts[i]; ca.cum[i] = cum; cum += ns[i] / 4; }
    ca.cum[NCONV] = cum;
    convert_many<<<(cum + 255) / 256, 256, 0, stream>>>(ca, cum);
    fill_bias2<<<8, 256, 0, stream>>>(F(20), F(22), BIAS2);

    const int M4 = B_ * S_;
    const int MA = B_ * SAUG;
    const float sc32 = 0.17677669529663687f;
    const float sc64 = 0.125f;
    const long long bsQKV = (long long)S_ * 3 * CNN_DIM;
    const long long bsATT = (long long)S_ * CNN_DIM;
    const long long bsAUG = (long long)SAUG * BR_DIM;
    const long long bsPQK = (long long)SAUG * 2048;
    const long long bsO   = (long long)S_ * BR_DIM;
    const int KP32 = 1024;
    const int KP64 = 1088;
    dim3 ablock(256);
    dim3 agrid4(S_ / 128, NH, B_), agrid8(S_ / 128, NH, 2 * B_);
    dim3 tgrid32(16, NH, B_), tgrid64(17, NH, 2 * B_);

    // ---- MHA 1 (spatial) ----
    gemm<0>(stream, CNN_B, W_SA_QKV, F(4), nullptr, QKV, M4, 3 * CNN_DIM, CNN_DIM);
    transpose_v<32, false><<<tgrid32, 256, 0, stream>>>(QKV + 2 * CNN_DIM, VT32, nullptr, S_, 3 * CNN_DIM, bsQKV, KP32);
    attn9<32, false, 2><<<agrid4, ablock, 0, stream>>>(QKV, QKV + CNN_DIM, VT32, nullptr, ATT,
        S_, 3 * CNN_DIM, 3 * CNN_DIM, CNN_DIM, bsQKV, bsQKV, bsATT, KP32, sc32);
    gemm<2>(stream, ATT, W_SA_O, F(6), F(2), CNN1, M4, CNN_DIM, CNN_DIM);

    // ---- MHA 2 (temporal) ----
    gemm<0>(stream, CNN1, W_TA_QKV, F(8), nullptr, QKV, M4, 3 * CNN_DIM, CNN_DIM);
    transpose_v<32, false><<<tgrid32, 256, 0, stream>>>(QKV + 2 * CNN_DIM, VT32, nullptr, S_, 3 * CNN_DIM, bsQKV, KP32);
    attn9<32, false, 2><<<agrid4, ablock, 0, stream>>>(QKV, QKV + CNN_DIM, VT32, nullptr, ATT,
        S_, 3 * CNN_DIM, 3 * CNN_DIM, CNN_DIM, bsQKV, bsQKV, bsATT, KP32, sc32);
    gemm<1>(stream, ATT, W_TA_O, F(10), CNN1, CNN2, M4, CNN_DIM, CNN_DIM);

    // ---- bridges to BR_DIM (Linear -> GELU -> LN) ----
    gemm<0>(stream, LLM_B, W_L2B, F(16), nullptr, X8, M4, BR_DIM, LLM_DIM);
    ln_kernel<true, false, false><<<M4, 256, 0, stream>>>(X8, nullptr, F(17), F(18), AUGL,
        BR_DIM, S_, 0, 0, bsAUG, BR_DIM);
    gemm<0>(stream, CNN2, W_C2B, F(12), nullptr, X8, M4, BR_DIM, CNN_DIM);
    ln_kernel<true, false, false><<<M4, 256, 0, stream>>>(X8, nullptr, F(13), F(14), AUGC,
        BR_DIM, S_, 0, 0, bsAUG, BR_DIM);
    fill_phys_kernel<<<12, 256, 0, stream>>>(F(27), F(28), F(29), AUGC, AUGL);

    // ---- merged phys projections: fused Q|K (N=2048) + V, over [AUGC;AUGL] (M=8216) ----
    gemm<0>(stream, AUGC, W_PQ, BIAS2, nullptr, PQK_ALL, 2 * MA, 2048, BR_DIM);
    gemm<0>(stream, AUGC, W_PV, F(24), nullptr, PV_ALL, 2 * MA, BR_DIM, BR_DIM);
    transpose_v<64, true><<<tgrid64, 256, 0, stream>>>(PV_ALL, VTA, VTB, SAUG, BR_DIM, bsAUG, KP64);

    // ---- merged phys attention, QG=2 (z<4: cnn-q x llm-kv; z>=4: llm-q x cnn-kv) ----
    attn9<64, true, 2><<<agrid8, ablock, 0, stream>>>(PQK_ALL, PQK_ALL + 1024, VTA, VTB, OB_ALL,
        SAUG, 2048, 2048, BR_DIM, bsPQK, bsPQK, bsO, KP64, sc64);

    // ---- merged PO projection + residual LN ----
    gemm<0>(stream, OB_ALL, W_PO, F(26), nullptr, X8_ALL, 2 * M4, BR_DIM, BR_DIM);
    ln_kernel<false, true, false><<<2 * M4, 256, 0, stream>>>(X8_ALL, AUGC, F(30), F(31), CATT_ALL,
        BR_DIM, S_, bsAUG, BR_DIM, bsO, BR_DIM);

    // ---- final bridges (f32 to d_out) ----
    gemm<0>(stream, CATT_ALL, W_C2L, F(33), nullptr, X6, M4, LLM_DIM, BR_DIM);
    ln_kernel<true, false, true><<<M4, 256, 0, stream>>>(X6, nullptr, F(34), F(35),
        (void*)(outp + 2097152), LLM_DIM, S_, 0, 0, (long long)S_ * LLM_DIM, LLM_DIM);
    gemm<0>(stream, CATT_ALL + (size_t)M4 * BR_DIM, W_L2C, F(37), nullptr, X4, M4, CNN_DIM, BR_DIM);
    ln_kernel<true, false, true><<<M4, 256, 0, stream>>>(X4, nullptr, F(38), F(39),
        (void*)outp, CNN_DIM, S_, 0, 0, (long long)S_ * CNN_DIM, CNN_DIM);
}

// Round 16
// 456.098 us; speedup vs baseline: 1.0560x; 1.0040x over previous
//
#include <hip/hip_runtime.h>
#include <cstdint>
#include <cstddef>

#define B_    4
#define S_    1024
#define CNN_DIM 512
#define LLM_DIM 768
#define BR_DIM  1024
#define NH    16
#define SAUG  1027

typedef __attribute__((ext_vector_type(8))) short short8;
typedef __attribute__((ext_vector_type(4))) float f32x4;
typedef __attribute__((ext_vector_type(4))) unsigned short us4;
typedef unsigned short u16;
typedef unsigned int u32;
typedef unsigned long long u64;

__device__ __forceinline__ float bf2f(u16 h) {
    union { u32 u; float f; } c; c.u = ((u32)h) << 16; return c.f;
}
__device__ __forceinline__ u16 f2bf(float f) {
    union { u32 u; float f; } c; c.f = f;
    return (u16)((c.u + 0x7FFFu + ((c.u >> 16) & 1u)) >> 16);
}
__device__ __forceinline__ short f2bfS(float f) { return (short)f2bf(f); }
__device__ __forceinline__ u32 cvt_pk_bf16(float lo, float hi) {
    u32 r;
    asm("v_cvt_pk_bf16_f32 %0, %1, %2" : "=v"(r) : "v"(lo), "v"(hi));
    return r;
}

#define GLLDS(gp, lp) __builtin_amdgcn_global_load_lds( \
    (const __attribute__((address_space(1))) void*)(gp), \
    (__attribute__((address_space(3))) void*)(lp), 16, 0, 0)

// ---------------- batched f32 -> bf16 conversion ----------------
#define NCONV 14
struct ConvArgs { const float* src[NCONV]; u16* dst[NCONV]; int cum[NCONV + 1]; };

__global__ __launch_bounds__(256) void convert_many(ConvArgs a, int total4) {
    int idx = blockIdx.x * 256 + threadIdx.x;
    if (idx >= total4) return;
    int seg = 0;
#pragma unroll
    for (int i = 1; i < NCONV; i++) if (a.cum[i] <= idx) seg = i;
    int j = idx - a.cum[seg];
    float4 v = ((const float4*)a.src[seg])[j];
    us4 o;
    o[0] = f2bf(v.x); o[1] = f2bf(v.y); o[2] = f2bf(v.z); o[3] = f2bf(v.w);
    ((us4*)a.dst[seg])[j] = o;
}

// ---------------- fused bias for PQ|PK ----------------
__global__ __launch_bounds__(256) void fill_bias2(
    const float* __restrict__ b0, const float* __restrict__ b1, float* __restrict__ out)
{
    int i = blockIdx.x * 256 + threadIdx.x;
    if (i < 1024) out[i] = b0[i];
    else if (i < 2048) out[i] = b1[i - 1024];
}

// ---------------- GEMM v2 (64x128 tile) ----------------
template<int RESID>   // 0 none, 1 bf16, 2 f32
__global__ __launch_bounds__(256) void gemm2_kernel(
    const u16* __restrict__ A, const u16* __restrict__ W,
    const float* __restrict__ bias, const void* __restrict__ residp,
    u16* __restrict__ C, int M, int N, int K)
{
    __shared__ u16 smA[2][64 * 64];
    __shared__ u16 smB[2][128 * 64];

    const int tid = threadIdx.x;
    const int lane = tid & 63;
    const int w = tid >> 6;
    const int wm = w & 1, wn = w >> 1;
    const int mi = lane & 15, g = lane >> 4;
    const int m0 = blockIdx.y * 64;
    const int n0 = blockIdx.x * 128;
    const int lrow = lane >> 3;
    const int lcol = lane & 7;

    f32x4 acc[2][4] = {};
    const int nk = K >> 6;
    int cur = 0;

    auto stage = [&](int buf, int kt) {
        const int kbase = kt * 64;
#pragma unroll
        for (int i = 0; i < 6; i++) {
            int c = w * 6 + i;
            if (c < 8) {
                int row = c * 8 + lrow;
                int col16 = lcol ^ (row & 7);
                int grow = m0 + row; if (grow > M - 1) grow = M - 1;
                GLLDS(A + (size_t)grow * K + kbase + col16 * 8, &smA[buf][c * 512]);
            } else {
                int c8 = c - 8;
                int row = c8 * 8 + lrow;
                int col16 = lcol ^ (row & 7);
                GLLDS(W + (size_t)(n0 + row) * K + kbase + col16 * 8, &smB[buf][c8 * 512]);
            }
        }
    };

    stage(0, 0);
    __syncthreads();

    for (int kt = 0; kt < nk; ++kt) {
        if (kt + 1 < nk) stage(cur ^ 1, kt + 1);
#pragma unroll
        for (int h = 0; h < 2; h++) {
            short8 af[2], bf[4];
#pragma unroll
            for (int im = 0; im < 2; im++) {
                int row = wm * 32 + im * 16 + mi;
                af[im] = *(const short8*)&smA[cur][row * 64 + ((h * 4 + g) ^ (mi & 7)) * 8];
            }
#pragma unroll
            for (int in = 0; in < 4; in++) {
                int row = wn * 64 + in * 16 + mi;
                bf[in] = *(const short8*)&smB[cur][row * 64 + ((h * 4 + g) ^ (mi & 7)) * 8];
            }
#pragma unroll
            for (int im = 0; im < 2; im++)
#pragma unroll
                for (int in = 0; in < 4; in++)
                    acc[im][in] = __builtin_amdgcn_mfma_f32_16x16x32_bf16(af[im], bf[in], acc[im][in], 0, 0, 0);
        }
        __syncthreads();
        cur ^= 1;
    }

#pragma unroll
    for (int im = 0; im < 2; im++) {
#pragma unroll
        for (int r = 0; r < 4; r++) {
            int row = m0 + wm * 32 + im * 16 + g * 4 + r;
            if (row >= M) continue;
            size_t base = (size_t)row * N;
#pragma unroll
            for (int in = 0; in < 4; in++) {
                int col = n0 + wn * 64 + in * 16 + mi;
                float v = acc[im][in][r] + bias[col];
                if (RESID == 1) v += bf2f(((const u16*)residp)[base + col]);
                if (RESID == 2) v += ((const float*)residp)[base + col];
                C[base + col] = f2bf(v);
            }
        }
    }
}

// ---------------- V transpose: V[gb][key][h*DH+d] -> VT[gb][h][d][KPAD] (optional split halves) ----------------
template<int DH, bool SPLIT>
__global__ __launch_bounds__(256) void transpose_v(
    const u16* __restrict__ Vin, u16* __restrict__ VTa, u16* __restrict__ VTb,
    int Sk, int in_rs, long long in_bs, int KPAD)
{
    __shared__ u16 tile[64][DH + 8];
    const int tid = threadIdx.x;
    const int gb = blockIdx.z, h = blockIdx.y;
    const int k0 = blockIdx.x * 64;
    const u16* src = Vin + (size_t)gb * in_bs + h * DH;

    constexpr int CH = DH / 8;
    for (int i = tid; i < 64 * CH; i += 256) {
        int key = i / CH, c = i % CH;
        short8 v = {0,0,0,0,0,0,0,0};
        if (k0 + key < Sk) v = *(const short8*)(src + (size_t)(k0 + key) * in_rs + c * 8);
        *(short8*)&tile[key][c * 8] = v;
    }
    __syncthreads();

    u16* base;
    if (SPLIT) base = (gb < 4) ? (VTa + ((size_t)(gb * NH + h) * DH) * KPAD)
                               : (VTb + ((size_t)((gb - 4) * NH + h) * DH) * KPAD);
    else       base = VTa + ((size_t)(gb * NH + h) * DH) * KPAD;
    u16* dst = base + k0;
    for (int i = tid; i < DH * 8; i += 256) {
        int d = i >> 3, c = i & 7;
        short8 o;
#pragma unroll
        for (int j = 0; j < 8; j++) o[j] = (short)tile[c * 8 + j][d];
        *(short8*)(dst + (size_t)d * KPAD + c * 8) = o;
    }
}

// ---------------- MFMA flash attention v9: double-buffered LDS, 1 barrier/tile ----------------
template<int DH, bool PHYS, int QG>
__global__ __launch_bounds__(256) void attn9(
    const u16* __restrict__ Q, const u16* __restrict__ Kb,
    const u16* __restrict__ VTa, const u16* __restrict__ VTb,
    u16* __restrict__ Ob, int Sk, int q_rs, int kv_rs, int o_rs,
    long long q_bs, long long kv_bs, long long o_bs, int KPAD, float scale)
{
    constexpr int KT = 32;
    constexpr int NDB = DH / 16;
    constexpr int NCH = DH / 32;
    constexpr int KLDP = DH + 8;
    constexpr int VLDP = 40;
    __shared__ __align__(16) u16 Kt[2][KT][KLDP];
    __shared__ __align__(16) u16 Vt[2][DH][VLDP];
    __shared__ __align__(16) u64 Px[4][16][10];

    const int tid = threadIdx.x;
    const int lane = tid & 63;
    const int w = tid >> 6;
    const int mi = lane & 15, g = lane >> 4;
    const int z = blockIdx.z, h = blockIdx.y;
    const int hoff = h * DH;
    const int qw = blockIdx.x * (64 * QG) + w * 16;
    const float sc2 = scale * 1.44269504088896f;

    int kb, vg;
    const u16* vts;
    if (PHYS) {
        kb = (z < 4) ? z + 4 : z - 4;
        vts = (z < 4) ? VTb : VTa;
        vg = (z < 4) ? z : z - 4;
    } else { kb = z; vts = VTa; vg = z; }

    int krow, kseg; bool kact;
    int vd, vks;   bool vact;
    if (DH == 64) { krow = tid >> 3; kseg = tid & 7; kact = true;
                    vd = tid >> 2;   vks = tid & 3;  vact = true; }
    else          { krow = tid >> 2; kseg = tid & 3; kact = (tid < 128);
                    vd = (tid - 128) >> 2; vks = tid & 3; vact = (tid >= 128); }

    short8 qfrag[QG][NCH];
#pragma unroll
    for (int qg = 0; qg < QG; qg++) {
        const u16* qs = Q + (size_t)z * q_bs + (size_t)(qw + qg * 64 + mi) * q_rs + hoff + g * 8;
#pragma unroll
        for (int c = 0; c < NCH; c++) {
            short8 q8 = *(const short8*)(qs + 32 * c);
#pragma unroll
            for (int j = 0; j < 8; j++) q8[j] = f2bfS(bf2f((u16)q8[j]) * sc2);
            qfrag[qg][c] = q8;
        }
    }

    const short one = (short)0x3F80;
    const short8 ones8 = {one, one, one, one, one, one, one, one};

    f32x4 acc[QG][NDB] = {};
    f32x4 accl[QG] = {};
    const u16* kbb = Kb + (size_t)kb * kv_bs + hoff;
    const u16* vtb = vts + ((size_t)(vg * NH + h) * DH) * KPAD;

    const int nt = (Sk + KT - 1) / KT;

    short8 kr8 = {0,0,0,0,0,0,0,0}, vr8 = {0,0,0,0,0,0,0,0};
    auto loadKV = [&](int t) {
        if (kact) {
            int key = t * KT + krow; if (key > Sk - 1) key = Sk - 1;
            kr8 = *(const short8*)(kbb + (size_t)key * kv_rs + kseg * 8);
        }
        if (vact)
            vr8 = *(const short8*)(vtb + (size_t)vd * KPAD + t * KT + vks * 8);
    };

    // prologue: tile 0 -> LDS[0]; prefetch tile 1 into regs
    loadKV(0);
    if (kact) *(short8*)&Kt[0][krow][kseg * 8] = kr8;
    if (vact) *(short8*)&Vt[0][vd][vks * 8] = vr8;
    if (nt > 1) loadKV(1);
    __syncthreads();

    for (int t = 0; t < nt; t++) {
        const int rem = Sk - t * KT;
        const int cur = t & 1;
        // write tile t+1 into the other buffer (its last readers finished at t-1,
        // separated by the barrier at end of t-1); prefetch tile t+2 into regs
        if (t + 1 < nt) {
            const int nb = cur ^ 1;
            if (kact) *(short8*)&Kt[nb][krow][kseg * 8] = kr8;
            if (vact) *(short8*)&Vt[nb][vd][vks * 8] = vr8;
            if (t + 2 < nt) loadKV(t + 2);
        }

        // ---- hoisted K and V fragments (shared across q-groups) ----
        short8 ka[NCH], kb8[NCH], vf[NDB];
#pragma unroll
        for (int c = 0; c < NCH; c++) {
            ka[c]  = *(const short8*)&Kt[cur][mi][g * 8 + 32 * c];
            kb8[c] = *(const short8*)&Kt[cur][16 + mi][g * 8 + 32 * c];
        }
#pragma unroll
        for (int db = 0; db < NDB; db++)
            vf[db] = *(const short8*)&Vt[cur][db * 16 + mi][g * 8];

#pragma unroll
        for (int qg = 0; qg < QG; qg++) {
            // ---- QK^T ----
            f32x4 sA = {0,0,0,0}, sB = {0,0,0,0};
#pragma unroll
            for (int c = 0; c < NCH; c++) {
                sA = __builtin_amdgcn_mfma_f32_16x16x32_bf16(ka[c],  qfrag[qg][c], sA, 0, 0, 0);
                sB = __builtin_amdgcn_mfma_f32_16x16x32_bf16(kb8[c], qfrag[qg][c], sB, 0, 0, 0);
            }

            // ---- no-max softmax terms ----
            float pa[4], pb[4];
            if (rem >= KT) {
#pragma unroll
                for (int r = 0; r < 4; r++) {
                    pa[r] = exp2f(sA[r]);
                    pb[r] = exp2f(sB[r]);
                }
            } else {
#pragma unroll
                for (int r = 0; r < 4; r++) {
                    pa[r] = (4 * g + r < rem)      ? exp2f(sA[r]) : 0.f;
                    pb[r] = (16 + 4 * g + r < rem) ? exp2f(sB[r]) : 0.f;
                }
            }

            // ---- P exchange (wave-internal LDS) ----
            {
                uint2 wa, wb;
                wa.x = cvt_pk_bf16(pa[0], pa[1]);
                wa.y = cvt_pk_bf16(pa[2], pa[3]);
                wb.x = cvt_pk_bf16(pb[0], pb[1]);
                wb.y = cvt_pk_bf16(pb[2], pb[3]);
                uint2* prow = (uint2*)&Px[w][mi][0];
                prow[g] = wa;
                prow[4 + g] = wb;
            }
            short8 pfrag = *(const short8*)((const u16*)&Px[w][mi][0] + 8 * g);

            // ---- denominator + PV ----
            accl[qg] = __builtin_amdgcn_mfma_f32_16x16x32_bf16(ones8, pfrag, accl[qg], 0, 0, 0);
#pragma unroll
            for (int db = 0; db < NDB; db++)
                acc[qg][db] = __builtin_amdgcn_mfma_f32_16x16x32_bf16(vf[db], pfrag, acc[qg][db], 0, 0, 0);
        }
        __syncthreads();   // single barrier per tile
    }

#pragma unroll
    for (int qg = 0; qg < QG; qg++) {
        const float inv = 1.f / accl[qg][0];
        u16* obase = Ob + (size_t)z * o_bs + (size_t)(qw + qg * 64 + mi) * o_rs + hoff;
#pragma unroll
        for (int db = 0; db < NDB; db++)
#pragma unroll
            for (int r = 0; r < 4; r++)
                obase[db * 16 + 4 * g + r] = f2bf(acc[qg][db][r] * inv);
    }
}

// ---------------- LayerNorm (vectorized) ----------------
template<bool GELU, bool RESID, bool OUTF32>
__global__ __launch_bounds__(256) void ln_kernel(
    const u16* __restrict__ X, const u16* __restrict__ resid,
    const float* __restrict__ gg, const float* __restrict__ be,
    void* __restrict__ out, int N, int rows_per_batch,
    long long resid_bs, int resid_rs, long long out_bs, int out_rs)
{
    __shared__ float buf[1024];
    __shared__ float red[2][4];
    __shared__ float stat[2];
    const int row = blockIdx.x;
    const int b = row / rows_per_batch, r = row % rows_per_batch;
    const int tid = threadIdx.x, lane = tid & 63, w = tid >> 6;
    const u16* xr = X + (size_t)row * N;
    const u16* rr = RESID ? (resid + (size_t)b * resid_bs + (size_t)r * resid_rs) : (const u16*)nullptr;

    float s = 0.f, s2 = 0.f;
    for (int i0 = tid * 4; i0 < N; i0 += 1024) {
        us4 xv = *(const us4*)(xr + i0);
        us4 rv = {0,0,0,0};
        if (RESID) rv = *(const us4*)(rr + i0);
        float4 xb;
        float* xp = &xb.x;
#pragma unroll
        for (int u = 0; u < 4; u++) {
            float x = bf2f(xv[u]);
            if (RESID) x += bf2f(rv[u]);
            if (GELU)  x = 0.5f * x * (1.f + erff(x * 0.70710678118654752f));
            xp[u] = x; s += x; s2 += x * x;
        }
        *(float4*)&buf[i0] = xb;
    }
#pragma unroll
    for (int off = 32; off; off >>= 1) { s += __shfl_xor(s, off); s2 += __shfl_xor(s2, off); }
    if (lane == 0) { red[0][w] = s; red[1][w] = s2; }
    __syncthreads();
    if (tid == 0) {
        float a = red[0][0] + red[0][1] + red[0][2] + red[0][3];
        float q = red[1][0] + red[1][1] + red[1][2] + red[1][3];
        float mean = a / N;
        float var = q / N - mean * mean;
        stat[0] = mean; stat[1] = rsqrtf(var + 1e-5f);
    }
    __syncthreads();
    const float mean = stat[0], rs = stat[1];
    const size_t obase = (size_t)b * out_bs + (size_t)r * out_rs;
    for (int i0 = tid * 4; i0 < N; i0 += 1024) {
        if (OUTF32) {
            float4 o;
            o.x = (buf[i0+0] - mean) * rs * gg[i0+0] + be[i0+0];
            o.y = (buf[i0+1] - mean) * rs * gg[i0+1] + be[i0+1];
            o.z = (buf[i0+2] - mean) * rs * gg[i0+2] + be[i0+2];
            o.w = (buf[i0+3] - mean) * rs * gg[i0+3] + be[i0+3];
            *(float4*)((float*)out + obase + i0) = o;
        } else {
            us4 o;
#pragma unroll
            for (int u = 0; u < 4; u++)
                o[u] = f2bf((buf[i0+u] - mean) * rs * gg[i0+u] + be[i0+u]);
            *(us4*)((u16*)out + obase + i0) = o;
        }
    }
}

// ---------------- phys embedding rows (f32 src -> bf16) ----------------
__global__ __launch_bounds__(256) void fill_phys_kernel(
    const float* __restrict__ e, const float* __restrict__ m, const float* __restrict__ p,
    u16* __restrict__ augc, u16* __restrict__ augl)
{
    int i = blockIdx.x * 256 + threadIdx.x;
    if (i >= 3 * BR_DIM) return;
    int r = i / BR_DIM, j = i % BR_DIM;
    u16 v = f2bf((r == 0) ? e[j] : (r == 1) ? m[j] : p[j]);
#pragma unroll
    for (int b = 0; b < B_; b++) {
        size_t off = ((size_t)b * SAUG + S_ + r) * BR_DIM + j;
        augc[off] = v; augl[off] = v;
    }
}

template<int RESID>
static void gemm(hipStream_t s, const u16* A, const u16* W, const float* bias,
                 const void* resid, u16* C, int M, int N, int K)
{
    dim3 grid(N / 128, (M + 63) / 64), block(256);
    gemm2_kernel<RESID><<<grid, block, 0, s>>>(A, W, bias, resid, C, M, N, K);
}

extern "C" void kernel_launch(void* const* d_in, const int* in_sizes, int n_in,
                              void* d_out, int out_size, void* d_ws, size_t ws_size,
                              hipStream_t stream)
{
    auto F = [&](int i) { return (const float*)d_in[i]; };
    uint8_t* ws = (uint8_t*)d_ws;

    // ---- workspace layout (high-water 103,956,736 B; proven rounds 12-15) ----
    u16* W_SA_QKV = (u16*)(ws + 256);
    u16* W_SA_O   = (u16*)(ws + 1573120);
    u16* W_TA_QKV = (u16*)(ws + 2097408);
    u16* W_TA_O   = (u16*)(ws + 3670272);
    u16* W_C2B    = (u16*)(ws + 4194560);
    u16* W_L2B    = (u16*)(ws + 5243136);
    u16* W_PQ     = (u16*)(ws + 6816000);   // W_PQ|W_PK contiguous => fused [2048][1024]
    u16* W_PK     = (u16*)(ws + 8913152);
    u16* W_PV     = (u16*)(ws + 11010304);
    u16* W_PO     = (u16*)(ws + 13107456);
    u16* W_C2L    = (u16*)(ws + 15204608);
    u16* W_L2C    = (u16*)(ws + 16777472);
    u16* VT32     = (u16*)(ws + 17826048);   // 4 MB (MHA V^T; CNN_B region)
    u16* CNN_B    = (u16*)(ws + 17826048);   // dead after MHA1 QKV gemm
    u16* LLM_B    = (u16*)(ws + 22020352);   // dead after l2b gemm
    u16* QKV      = (u16*)(ws + 28311808);   // 12.6 MB; X8 bridge scratch alias
    u16* ATT      = (u16*)(ws + 40894720);   // 4 MB
    u16* CNN1     = (u16*)(ws + 45089024);
    u16* CNN2     = (u16*)(ws + 49283328);
    u16* AUGC     = (u16*)(ws + 53477632);   // 8 batches contiguous w/ AUGL
    u16* AUGL     = (u16*)(ws + 61890816);   // end 70,304,000
    u16* VTA      = (u16*)(ws + 17826048);   // 8.9 MB (phys V^T groups 0-3; over dead CNN_B/LLM_B)
    u16* PV_ALL   = (u16*)(ws + 26738944);   // 16.8 MB, end 43,565,312 (over dead QKV/ATT)
    u16* VTB      = (u16*)(ws + 43565312);   // 8.9 MB, end 52,478,208
    float* BIAS2  = (float*)(ws + 52478208); // 8 KB fused PQ|PK bias
    u16* OB_ALL   = (u16*)(ws + 26738944);   // over dead PV_ALL
    u16* PQK_ALL  = (u16*)(ws + 70304000);   // [8216][2048] = 33.65 MB, end 103,956,736
    u16* X8       = QKV;                     // bridge scratch (8 MB)
    u16* X8_ALL   = (u16*)(ws + 70304000);   // PO out, over dead PQK_ALL
    u16* CATT_ALL = (u16*)(ws + 87130368);   // 16.8 MB, end 103,956,736
    u16* X6       = (u16*)(ws + 26738944);   // over dead OB_ALL
    u16* X4       = (u16*)(ws + 26738944);
    float* outp   = (float*)d_out;

    // ---- convert weights + features to bf16 ----
    ConvArgs ca;
    const float* srcs[NCONV] = { F(1), F(2), F(3), F(5), F(7), F(9), F(11),
                                 F(15), F(19), F(21), F(23), F(25), F(32), F(36) };
    u16* dsts[NCONV] = { LLM_B, CNN_B, W_SA_QKV, W_SA_O, W_TA_QKV, W_TA_O, W_C2B,
                         W_L2B, W_PQ, W_PK, W_PV, W_PO, W_C2L, W_L2C };
    const int ns[NCONV] = { 3145728, 2097152, 786432, 262144, 786432, 262144, 524288,
                            786432, 1048576, 1048576, 1048576, 1048576, 786432, 524288 };
    int cum = 0;
    for (int i = 0; i < NCONV; i++) { ca.src[i] = srcs[i]; ca.dst[i] = dsts[i]; ca.cum[i] = cum; cum += ns[i] / 4; }
    ca.cum[NCONV] = cum;
    convert_many<<<(cum + 255) / 256, 256, 0, stream>>>(ca, cum);
    fill_bias2<<<8, 256, 0, stream>>>(F(20), F(22), BIAS2);

    const int M4 = B_ * S_;
    const int MA = B_ * SAUG;
    const float sc32 = 0.17677669529663687f;
    const float sc64 = 0.125f;
    const long long bsQKV = (long long)S_ * 3 * CNN_DIM;
    const long long bsATT = (long long)S_ * CNN_DIM;
    const long long bsAUG = (long long)SAUG * BR_DIM;
    const long long bsPQK = (long long)SAUG * 2048;
    const long long bsO   = (long long)S_ * BR_DIM;
    const int KP32 = 1024;
    const int KP64 = 1088;
    dim3 ablock(256);
    dim3 agrid4(S_ / 128, NH, B_), agrid8(S_ / 256, NH, 2 * B_);
    dim3 tgrid32(16, NH, B_), tgrid64(17, NH, 2 * B_);

    // ---- MHA 1 (spatial) ----
    gemm<0>(stream, CNN_B, W_SA_QKV, F(4), nullptr, QKV, M4, 3 * CNN_DIM, CNN_DIM);
    transpose_v<32, false><<<tgrid32, 256, 0, stream>>>(QKV + 2 * CNN_DIM, VT32, nullptr, S_, 3 * CNN_DIM, bsQKV, KP32);
    attn9<32, false, 2><<<agrid4, ablock, 0, stream>>>(QKV, QKV + CNN_DIM, VT32, nullptr, ATT,
        S_, 3 * CNN_DIM, 3 * CNN_DIM, CNN_DIM, bsQKV, bsQKV, bsATT, KP32, sc32);
    gemm<2>(stream, ATT, W_SA_O, F(6), F(2), CNN1, M4, CNN_DIM, CNN_DIM);

    // ---- MHA 2 (temporal) ----
    gemm<0>(stream, CNN1, W_TA_QKV, F(8), nullptr, QKV, M4, 3 * CNN_DIM, CNN_DIM);
    transpose_v<32, false><<<tgrid32, 256, 0, stream>>>(QKV + 2 * CNN_DIM, VT32, nullptr, S_, 3 * CNN_DIM, bsQKV, KP32);
    attn9<32, false, 2><<<agrid4, ablock, 0, stream>>>(QKV, QKV + CNN_DIM, VT32, nullptr, ATT,
        S_, 3 * CNN_DIM, 3 * CNN_DIM, CNN_DIM, bsQKV, bsQKV, bsATT, KP32, sc32);
    gemm<1>(stream, ATT, W_TA_O, F(10), CNN1, CNN2, M4, CNN_DIM, CNN_DIM);

    // ---- bridges to BR_DIM (Linear -> GELU -> LN) ----
    gemm<0>(stream, LLM_B, W_L2B, F(16), nullptr, X8, M4, BR_DIM, LLM_DIM);
    ln_kernel<true, false, false><<<M4, 256, 0, stream>>>(X8, nullptr, F(17), F(18), AUGL,
        BR_DIM, S_, 0, 0, bsAUG, BR_DIM);
    gemm<0>(stream, CNN2, W_C2B, F(12), nullptr, X8, M4, BR_DIM, CNN_DIM);
    ln_kernel<true, false, false><<<M4, 256, 0, stream>>>(X8, nullptr, F(13), F(14), AUGC,
        BR_DIM, S_, 0, 0, bsAUG, BR_DIM);
    fill_phys_kernel<<<12, 256, 0, stream>>>(F(27), F(28), F(29), AUGC, AUGL);

    // ---- merged phys projections: fused Q|K (N=2048) + V, over [AUGC;AUGL] (M=8216) ----
    gemm<0>(stream, AUGC, W_PQ, BIAS2, nullptr, PQK_ALL, 2 * MA, 2048, BR_DIM);
    gemm<0>(stream, AUGC, W_PV, F(24), nullptr, PV_ALL, 2 * MA, BR_DIM, BR_DIM);
    transpose_v<64, true><<<tgrid64, 256, 0, stream>>>(PV_ALL, VTA, VTB, SAUG, BR_DIM, bsAUG, KP64);

    // ---- merged phys attention, QG=4 + dbuf (z<4: cnn-q x llm-kv; z>=4: llm-q x cnn-kv) ----
    attn9<64, true, 4><<<agrid8, ablock, 0, stream>>>(PQK_ALL, PQK_ALL + 1024, VTA, VTB, OB_ALL,
        SAUG, 2048, 2048, BR_DIM, bsPQK, bsPQK, bsO, KP64, sc64);

    // ---- merged PO projection + residual LN ----
    gemm<0>(stream, OB_ALL, W_PO, F(26), nullptr, X8_ALL, 2 * M4, BR_DIM, BR_DIM);
    ln_kernel<false, true, false><<<2 * M4, 256, 0, stream>>>(X8_ALL, AUGC, F(30), F(31), CATT_ALL,
        BR_DIM, S_, bsAUG, BR_DIM, bsO, BR_DIM);

    // ---- final bridges (f32 to d_out) ----
    gemm<0>(stream, CATT_ALL, W_C2L, F(33), nullptr, X6, M4, LLM_DIM, BR_DIM);
    ln_kernel<true, false, true><<<M4, 256, 0, stream>>>(X6, nullptr, F(34), F(35),
        (void*)(outp + 2097152), LLM_DIM, S_, 0, 0, (long long)S_ * LLM_DIM, LLM_DIM);
    gemm<0>(stream, CATT_ALL + (size_t)M4 * BR_DIM, W_L2C, F(37), nullptr, X4, M4, CNN_DIM, BR_DIM);
    ln_kernel<true, false, true><<<M4, 256, 0, stream>>>(X4, nullptr, F(38), F(39),
        (void*)outp, CNN_DIM, S_, 0, 0, (long long)S_ * CNN_DIM, CNN_DIM);
}

// Round 17
// 455.997 us; speedup vs baseline: 1.0562x; 1.0002x over previous
//
#include <hip/hip_runtime.h>
#include <cstdint>
#include <cstddef>

#define B_    4
#define S_    1024
#define CNN_DIM 512
#define LLM_DIM 768
#define BR_DIM  1024
#define NH    16
#define SAUG  1027

typedef __attribute__((ext_vector_type(8))) short short8;
typedef __attribute__((ext_vector_type(4))) float f32x4;
typedef __attribute__((ext_vector_type(4))) unsigned short us4;
typedef unsigned short u16;
typedef unsigned int u32;
typedef unsigned long long u64;

__device__ __forceinline__ float bf2f(u16 h) {
    union { u32 u; float f; } c; c.u = ((u32)h) << 16; return c.f;
}
__device__ __forceinline__ u16 f2bf(float f) {
    union { u32 u; float f; } c; c.f = f;
    return (u16)((c.u + 0x7FFFu + ((c.u >> 16) & 1u)) >> 16);
}
__device__ __forceinline__ short f2bfS(float f) { return (short)f2bf(f); }
__device__ __forceinline__ u32 cvt_pk_bf16(float lo, float hi) {
    u32 r;
    asm("v_cvt_pk_bf16_f32 %0, %1, %2" : "=v"(r) : "v"(lo), "v"(hi));
    return r;
}

#define GLLDS(gp, lp) __builtin_amdgcn_global_load_lds( \
    (const __attribute__((address_space(1))) void*)(gp), \
    (__attribute__((address_space(3))) void*)(lp), 16, 0, 0)

// ---------------- batched f32 -> bf16 conversion ----------------
#define NCONV 14
struct ConvArgs { const float* src[NCONV]; u16* dst[NCONV]; int cum[NCONV + 1]; };

__global__ __launch_bounds__(256) void convert_many(ConvArgs a, int total4) {
    int idx = blockIdx.x * 256 + threadIdx.x;
    if (idx >= total4) return;
    int seg = 0;
#pragma unroll
    for (int i = 1; i < NCONV; i++) if (a.cum[i] <= idx) seg = i;
    int j = idx - a.cum[seg];
    float4 v = ((const float4*)a.src[seg])[j];
    us4 o;
    o[0] = f2bf(v.x); o[1] = f2bf(v.y); o[2] = f2bf(v.z); o[3] = f2bf(v.w);
    ((us4*)a.dst[seg])[j] = o;
}

// ---------------- fused bias for PQ|PK ----------------
__global__ __launch_bounds__(256) void fill_bias2(
    const float* __restrict__ b0, const float* __restrict__ b1, float* __restrict__ out)
{
    int i = blockIdx.x * 256 + threadIdx.x;
    if (i < 1024) out[i] = b0[i];
    else if (i < 2048) out[i] = b1[i - 1024];
}

// ---------------- GEMM v2 (64x128 tile) ----------------
template<int RESID>   // 0 none, 1 bf16, 2 f32
__global__ __launch_bounds__(256) void gemm2_kernel(
    const u16* __restrict__ A, const u16* __restrict__ W,
    const float* __restrict__ bias, const void* __restrict__ residp,
    u16* __restrict__ C, int M, int N, int K)
{
    __shared__ u16 smA[2][64 * 64];
    __shared__ u16 smB[2][128 * 64];

    const int tid = threadIdx.x;
    const int lane = tid & 63;
    const int w = tid >> 6;
    const int wm = w & 1, wn = w >> 1;
    const int mi = lane & 15, g = lane >> 4;
    const int m0 = blockIdx.y * 64;
    const int n0 = blockIdx.x * 128;
    const int lrow = lane >> 3;
    const int lcol = lane & 7;

    f32x4 acc[2][4] = {};
    const int nk = K >> 6;
    int cur = 0;

    auto stage = [&](int buf, int kt) {
        const int kbase = kt * 64;
#pragma unroll
        for (int i = 0; i < 6; i++) {
            int c = w * 6 + i;
            if (c < 8) {
                int row = c * 8 + lrow;
                int col16 = lcol ^ (row & 7);
                int grow = m0 + row; if (grow > M - 1) grow = M - 1;
                GLLDS(A + (size_t)grow * K + kbase + col16 * 8, &smA[buf][c * 512]);
            } else {
                int c8 = c - 8;
                int row = c8 * 8 + lrow;
                int col16 = lcol ^ (row & 7);
                GLLDS(W + (size_t)(n0 + row) * K + kbase + col16 * 8, &smB[buf][c8 * 512]);
            }
        }
    };

    stage(0, 0);
    __syncthreads();

    for (int kt = 0; kt < nk; ++kt) {
        if (kt + 1 < nk) stage(cur ^ 1, kt + 1);
#pragma unroll
        for (int h = 0; h < 2; h++) {
            short8 af[2], bf[4];
#pragma unroll
            for (int im = 0; im < 2; im++) {
                int row = wm * 32 + im * 16 + mi;
                af[im] = *(const short8*)&smA[cur][row * 64 + ((h * 4 + g) ^ (mi & 7)) * 8];
            }
#pragma unroll
            for (int in = 0; in < 4; in++) {
                int row = wn * 64 + in * 16 + mi;
                bf[in] = *(const short8*)&smB[cur][row * 64 + ((h * 4 + g) ^ (mi & 7)) * 8];
            }
#pragma unroll
            for (int im = 0; im < 2; im++)
#pragma unroll
                for (int in = 0; in < 4; in++)
                    acc[im][in] = __builtin_amdgcn_mfma_f32_16x16x32_bf16(af[im], bf[in], acc[im][in], 0, 0, 0);
        }
        __syncthreads();
        cur ^= 1;
    }

#pragma unroll
    for (int im = 0; im < 2; im++) {
#pragma unroll
        for (int r = 0; r < 4; r++) {
            int row = m0 + wm * 32 + im * 16 + g * 4 + r;
            if (row >= M) continue;
            size_t base = (size_t)row * N;
#pragma unroll
            for (int in = 0; in < 4; in++) {
                int col = n0 + wn * 64 + in * 16 + mi;
                float v = acc[im][in][r] + bias[col];
                if (RESID == 1) v += bf2f(((const u16*)residp)[base + col]);
                if (RESID == 2) v += ((const float*)residp)[base + col];
                C[base + col] = f2bf(v);
            }
        }
    }
}

// ---------------- V transpose: V[gb][key][h*DH+d] -> VT[gb][h][d][KPAD] (optional split halves) ----------------
template<int DH, bool SPLIT>
__global__ __launch_bounds__(256) void transpose_v(
    const u16* __restrict__ Vin, u16* __restrict__ VTa, u16* __restrict__ VTb,
    int Sk, int in_rs, long long in_bs, int KPAD)
{
    __shared__ u16 tile[64][DH + 8];
    const int tid = threadIdx.x;
    const int gb = blockIdx.z, h = blockIdx.y;
    const int k0 = blockIdx.x * 64;
    const u16* src = Vin + (size_t)gb * in_bs + h * DH;

    constexpr int CH = DH / 8;
    for (int i = tid; i < 64 * CH; i += 256) {
        int key = i / CH, c = i % CH;
        short8 v = {0,0,0,0,0,0,0,0};
        if (k0 + key < Sk) v = *(const short8*)(src + (size_t)(k0 + key) * in_rs + c * 8);
        *(short8*)&tile[key][c * 8] = v;
    }
    __syncthreads();

    u16* base;
    if (SPLIT) base = (gb < 4) ? (VTa + ((size_t)(gb * NH + h) * DH) * KPAD)
                               : (VTb + ((size_t)((gb - 4) * NH + h) * DH) * KPAD);
    else       base = VTa + ((size_t)(gb * NH + h) * DH) * KPAD;
    u16* dst = base + k0;
    for (int i = tid; i < DH * 8; i += 256) {
        int d = i >> 3, c = i & 7;
        short8 o;
#pragma unroll
        for (int j = 0; j < 8; j++) o[j] = (short)tile[c * 8 + j][d];
        *(short8*)(dst + (size_t)d * KPAD + c * 8) = o;
    }
}

// ---------------- MFMA flash attention v10: dbuf LDS + per-qg Px (deserialized chains) ----------------
template<int DH, bool PHYS, int QG>
__global__ __launch_bounds__(256) void attn10(
    const u16* __restrict__ Q, const u16* __restrict__ Kb,
    const u16* __restrict__ VTa, const u16* __restrict__ VTb,
    u16* __restrict__ Ob, int Sk, int q_rs, int kv_rs, int o_rs,
    long long q_bs, long long kv_bs, long long o_bs, int KPAD, float scale)
{
    constexpr int KT = 32;
    constexpr int NDB = DH / 16;
    constexpr int NCH = DH / 32;
    constexpr int KLDP = DH + 8;
    constexpr int VLDP = 40;
    __shared__ __align__(16) u16 Kt[2][KT][KLDP];
    __shared__ __align__(16) u16 Vt[2][DH][VLDP];
    __shared__ __align__(16) u64 Px[4][QG][16][10];   // per-wave, per-q-group

    const int tid = threadIdx.x;
    const int lane = tid & 63;
    const int w = tid >> 6;
    const int mi = lane & 15, g = lane >> 4;
    const int z = blockIdx.z, h = blockIdx.y;
    const int hoff = h * DH;
    const int qw = blockIdx.x * (64 * QG) + w * 16;
    const float sc2 = scale * 1.44269504088896f;

    int kb, vg;
    const u16* vts;
    if (PHYS) {
        kb = (z < 4) ? z + 4 : z - 4;
        vts = (z < 4) ? VTb : VTa;
        vg = (z < 4) ? z : z - 4;
    } else { kb = z; vts = VTa; vg = z; }

    int krow, kseg; bool kact;
    int vd, vks;   bool vact;
    if (DH == 64) { krow = tid >> 3; kseg = tid & 7; kact = true;
                    vd = tid >> 2;   vks = tid & 3;  vact = true; }
    else          { krow = tid >> 2; kseg = tid & 3; kact = (tid < 128);
                    vd = (tid - 128) >> 2; vks = tid & 3; vact = (tid >= 128); }

    short8 qfrag[QG][NCH];
#pragma unroll
    for (int qg = 0; qg < QG; qg++) {
        const u16* qs = Q + (size_t)z * q_bs + (size_t)(qw + qg * 64 + mi) * q_rs + hoff + g * 8;
#pragma unroll
        for (int c = 0; c < NCH; c++) {
            short8 q8 = *(const short8*)(qs + 32 * c);
#pragma unroll
            for (int j = 0; j < 8; j++) q8[j] = f2bfS(bf2f((u16)q8[j]) * sc2);
            qfrag[qg][c] = q8;
        }
    }

    const short one = (short)0x3F80;
    const short8 ones8 = {one, one, one, one, one, one, one, one};

    f32x4 acc[QG][NDB] = {};
    f32x4 accl[QG] = {};
    const u16* kbb = Kb + (size_t)kb * kv_bs + hoff;
    const u16* vtb = vts + ((size_t)(vg * NH + h) * DH) * KPAD;

    const int nt = (Sk + KT - 1) / KT;

    short8 kr8 = {0,0,0,0,0,0,0,0}, vr8 = {0,0,0,0,0,0,0,0};
    auto loadKV = [&](int t) {
        if (kact) {
            int key = t * KT + krow; if (key > Sk - 1) key = Sk - 1;
            kr8 = *(const short8*)(kbb + (size_t)key * kv_rs + kseg * 8);
        }
        if (vact)
            vr8 = *(const short8*)(vtb + (size_t)vd * KPAD + t * KT + vks * 8);
    };

    // prologue: tile 0 -> LDS[0]; prefetch tile 1 into regs
    loadKV(0);
    if (kact) *(short8*)&Kt[0][krow][kseg * 8] = kr8;
    if (vact) *(short8*)&Vt[0][vd][vks * 8] = vr8;
    if (nt > 1) loadKV(1);
    __syncthreads();

    for (int t = 0; t < nt; t++) {
        const int rem = Sk - t * KT;
        const int cur = t & 1;
        if (t + 1 < nt) {
            const int nb = cur ^ 1;
            if (kact) *(short8*)&Kt[nb][krow][kseg * 8] = kr8;
            if (vact) *(short8*)&Vt[nb][vd][vks * 8] = vr8;
            if (t + 2 < nt) loadKV(t + 2);
        }

        // ---- hoisted K and V fragments (shared across q-groups) ----
        short8 ka[NCH], kb8[NCH], vf[NDB];
#pragma unroll
        for (int c = 0; c < NCH; c++) {
            ka[c]  = *(const short8*)&Kt[cur][mi][g * 8 + 32 * c];
            kb8[c] = *(const short8*)&Kt[cur][16 + mi][g * 8 + 32 * c];
        }
#pragma unroll
        for (int db = 0; db < NDB; db++)
            vf[db] = *(const short8*)&Vt[cur][db * 16 + mi][g * 8];

        // ---- phase 1: all q-groups QK^T + exp2 + pack + Px write (independent slots) ----
#pragma unroll
        for (int qg = 0; qg < QG; qg++) {
            f32x4 sA = {0,0,0,0}, sB = {0,0,0,0};
#pragma unroll
            for (int c = 0; c < NCH; c++) {
                sA = __builtin_amdgcn_mfma_f32_16x16x32_bf16(ka[c],  qfrag[qg][c], sA, 0, 0, 0);
                sB = __builtin_amdgcn_mfma_f32_16x16x32_bf16(kb8[c], qfrag[qg][c], sB, 0, 0, 0);
            }
            float pa[4], pb[4];
            if (rem >= KT) {
#pragma unroll
                for (int r = 0; r < 4; r++) {
                    pa[r] = exp2f(sA[r]);
                    pb[r] = exp2f(sB[r]);
                }
            } else {
#pragma unroll
                for (int r = 0; r < 4; r++) {
                    pa[r] = (4 * g + r < rem)      ? exp2f(sA[r]) : 0.f;
                    pb[r] = (16 + 4 * g + r < rem) ? exp2f(sB[r]) : 0.f;
                }
            }
            uint2 wa, wb;
            wa.x = cvt_pk_bf16(pa[0], pa[1]);
            wa.y = cvt_pk_bf16(pa[2], pa[3]);
            wb.x = cvt_pk_bf16(pb[0], pb[1]);
            wb.y = cvt_pk_bf16(pb[2], pb[3]);
            uint2* prow = (uint2*)&Px[w][qg][mi][0];
            prow[g] = wa;
            prow[4 + g] = wb;
        }

        // ---- phase 2: all q-groups Px read + denominator + PV ----
#pragma unroll
        for (int qg = 0; qg < QG; qg++) {
            short8 pfrag = *(const short8*)((const u16*)&Px[w][qg][mi][0] + 8 * g);
            accl[qg] = __builtin_amdgcn_mfma_f32_16x16x32_bf16(ones8, pfrag, accl[qg], 0, 0, 0);
#pragma unroll
            for (int db = 0; db < NDB; db++)
                acc[qg][db] = __builtin_amdgcn_mfma_f32_16x16x32_bf16(vf[db], pfrag, acc[qg][db], 0, 0, 0);
        }
        __syncthreads();   // single barrier per tile
    }

#pragma unroll
    for (int qg = 0; qg < QG; qg++) {
        const float inv = 1.f / accl[qg][0];
        u16* obase = Ob + (size_t)z * o_bs + (size_t)(qw + qg * 64 + mi) * o_rs + hoff;
#pragma unroll
        for (int db = 0; db < NDB; db++) {
            us4 o4;
#pragma unroll
            for (int r = 0; r < 4; r++) o4[r] = f2bf(acc[qg][db][r] * inv);
            *(us4*)(obase + db * 16 + 4 * g) = o4;   // 4*g is 8B-aligned offset
        }
    }
}

// ---------------- LayerNorm (vectorized) ----------------
template<bool GELU, bool RESID, bool OUTF32>
__global__ __launch_bounds__(256) void ln_kernel(
    const u16* __restrict__ X, const u16* __restrict__ resid,
    const float* __restrict__ gg, const float* __restrict__ be,
    void* __restrict__ out, int N, int rows_per_batch,
    long long resid_bs, int resid_rs, long long out_bs, int out_rs)
{
    __shared__ float buf[1024];
    __shared__ float red[2][4];
    __shared__ float stat[2];
    const int row = blockIdx.x;
    const int b = row / rows_per_batch, r = row % rows_per_batch;
    const int tid = threadIdx.x, lane = tid & 63, w = tid >> 6;
    const u16* xr = X + (size_t)row * N;
    const u16* rr = RESID ? (resid + (size_t)b * resid_bs + (size_t)r * resid_rs) : (const u16*)nullptr;

    float s = 0.f, s2 = 0.f;
    for (int i0 = tid * 4; i0 < N; i0 += 1024) {
        us4 xv = *(const us4*)(xr + i0);
        us4 rv = {0,0,0,0};
        if (RESID) rv = *(const us4*)(rr + i0);
        float4 xb;
        float* xp = &xb.x;
#pragma unroll
        for (int u = 0; u < 4; u++) {
            float x = bf2f(xv[u]);
            if (RESID) x += bf2f(rv[u]);
            if (GELU)  x = 0.5f * x * (1.f + erff(x * 0.70710678118654752f));
            xp[u] = x; s += x; s2 += x * x;
        }
        *(float4*)&buf[i0] = xb;
    }
#pragma unroll
    for (int off = 32; off; off >>= 1) { s += __shfl_xor(s, off); s2 += __shfl_xor(s2, off); }
    if (lane == 0) { red[0][w] = s; red[1][w] = s2; }
    __syncthreads();
    if (tid == 0) {
        float a = red[0][0] + red[0][1] + red[0][2] + red[0][3];
        float q = red[1][0] + red[1][1] + red[1][2] + red[1][3];
        float mean = a / N;
        float var = q / N - mean * mean;
        stat[0] = mean; stat[1] = rsqrtf(var + 1e-5f);
    }
    __syncthreads();
    const float mean = stat[0], rs = stat[1];
    const size_t obase = (size_t)b * out_bs + (size_t)r * out_rs;
    for (int i0 = tid * 4; i0 < N; i0 += 1024) {
        if (OUTF32) {
            float4 o;
            o.x = (buf[i0+0] - mean) * rs * gg[i0+0] + be[i0+0];
            o.y = (buf[i0+1] - mean) * rs * gg[i0+1] + be[i0+1];
            o.z = (buf[i0+2] - mean) * rs * gg[i0+2] + be[i0+2];
            o.w = (buf[i0+3] - mean) * rs * gg[i0+3] + be[i0+3];
            *(float4*)((float*)out + obase + i0) = o;
        } else {
            us4 o;
#pragma unroll
            for (int u = 0; u < 4; u++)
                o[u] = f2bf((buf[i0+u] - mean) * rs * gg[i0+u] + be[i0+u]);
            *(us4*)((u16*)out + obase + i0) = o;
        }
    }
}

// ---------------- phys embedding rows (f32 src -> bf16) ----------------
__global__ __launch_bounds__(256) void fill_phys_kernel(
    const float* __restrict__ e, const float* __restrict__ m, const float* __restrict__ p,
    u16* __restrict__ augc, u16* __restrict__ augl)
{
    int i = blockIdx.x * 256 + threadIdx.x;
    if (i >= 3 * BR_DIM) return;
    int r = i / BR_DIM, j = i % BR_DIM;
    u16 v = f2bf((r == 0) ? e[j] : (r == 1) ? m[j] : p[j]);
#pragma unroll
    for (int b = 0; b < B_; b++) {
        size_t off = ((size_t)b * SAUG + S_ + r) * BR_DIM + j;
        augc[off] = v; augl[off] = v;
    }
}

template<int RESID>
static void gemm(hipStream_t s, const u16* A, const u16* W, const float* bias,
                 const void* resid, u16* C, int M, int N, int K)
{
    dim3 grid(N / 128, (M + 63) / 64), block(256);
    gemm2_kernel<RESID><<<grid, block, 0, s>>>(A, W, bias, resid, C, M, N, K);
}

extern "C" void kernel_launch(void* const* d_in, const int* in_sizes, int n_in,
                              void* d_out, int out_size, void* d_ws, size_t ws_size,
                              hipStream_t stream)
{
    auto F = [&](int i) { return (const float*)d_in[i]; };
    uint8_t* ws = (uint8_t*)d_ws;

    // ---- workspace layout (high-water 103,956,736 B; proven rounds 12-16) ----
    u16* W_SA_QKV = (u16*)(ws + 256);
    u16* W_SA_O   = (u16*)(ws + 1573120);
    u16* W_TA_QKV = (u16*)(ws + 2097408);
    u16* W_TA_O   = (u16*)(ws + 3670272);
    u16* W_C2B    = (u16*)(ws + 4194560);
    u16* W_L2B    = (u16*)(ws + 5243136);
    u16* W_PQ     = (u16*)(ws + 6816000);   // W_PQ|W_PK contiguous => fused [2048][1024]
    u16* W_PK     = (u16*)(ws + 8913152);
    u16* W_PV     = (u16*)(ws + 11010304);
    u16* W_PO     = (u16*)(ws + 13107456);
    u16* W_C2L    = (u16*)(ws + 15204608);
    u16* W_L2C    = (u16*)(ws + 16777472);
    u16* VT32     = (u16*)(ws + 17826048);   // 4 MB (MHA V^T; CNN_B region)
    u16* CNN_B    = (u16*)(ws + 17826048);   // dead after MHA1 QKV gemm
    u16* LLM_B    = (u16*)(ws + 22020352);   // dead after l2b gemm
    u16* QKV      = (u16*)(ws + 28311808);   // 12.6 MB; X8 bridge scratch alias
    u16* ATT      = (u16*)(ws + 40894720);   // 4 MB
    u16* CNN1     = (u16*)(ws + 45089024);
    u16* CNN2     = (u16*)(ws + 49283328);
    u16* AUGC     = (u16*)(ws + 53477632);   // 8 batches contiguous w/ AUGL
    u16* AUGL     = (u16*)(ws + 61890816);   // end 70,304,000
    u16* VTA      = (u16*)(ws + 17826048);   // 8.9 MB (phys V^T groups 0-3; over dead CNN_B/LLM_B)
    u16* PV_ALL   = (u16*)(ws + 26738944);   // 16.8 MB, end 43,565,312 (over dead QKV/ATT)
    u16* VTB      = (u16*)(ws + 43565312);   // 8.9 MB, end 52,478,208
    float* BIAS2  = (float*)(ws + 52478208); // 8 KB fused PQ|PK bias
    u16* OB_ALL   = (u16*)(ws + 26738944);   // over dead PV_ALL
    u16* PQK_ALL  = (u16*)(ws + 70304000);   // [8216][2048] = 33.65 MB, end 103,956,736
    u16* X8       = QKV;                     // bridge scratch (8 MB)
    u16* X8_ALL   = (u16*)(ws + 70304000);   // PO out, over dead PQK_ALL
    u16* CATT_ALL = (u16*)(ws + 87130368);   // 16.8 MB, end 103,956,736
    u16* X6       = (u16*)(ws + 26738944);   // over dead OB_ALL
    u16* X4       = (u16*)(ws + 26738944);
    float* outp   = (float*)d_out;

    // ---- convert weights + features to bf16 ----
    ConvArgs ca;
    const float* srcs[NCONV] = { F(1), F(2), F(3), F(5), F(7), F(9), F(11),
                                 F(15), F(19), F(21), F(23), F(25), F(32), F(36) };
    u16* dsts[NCONV] = { LLM_B, CNN_B, W_SA_QKV, W_SA_O, W_TA_QKV, W_TA_O, W_C2B,
                         W_L2B, W_PQ, W_PK, W_PV, W_PO, W_C2L, W_L2C };
    const int ns[NCONV] = { 3145728, 2097152, 786432, 262144, 786432, 262144, 524288,
                            786432, 1048576, 1048576, 1048576, 1048576, 786432, 524288 };
    int cum = 0;
    for (int i = 0; i < NCONV; i++) { ca.src[i] = srcs[i]; ca.dst[i] = dsts[i]; ca.cum[i] = cum; cum += ns[i] / 4; }
    ca.cum[NCONV] = cum;
    convert_many<<<(cum + 255) / 256, 256, 0, stream>>>(ca, cum);
    fill_bias2<<<8, 256, 0, stream>>>(F(20), F(22), BIAS2);

    const int M4 = B_ * S_;
    const int MA = B_ * SAUG;
    const float sc32 = 0.17677669529663687f;
    const float sc64 = 0.125f;
    const long long bsQKV = (long long)S_ * 3 * CNN_DIM;
    const long long bsATT = (long long)S_ * CNN_DIM;
    const long long bsAUG = (long long)SAUG * BR_DIM;
    const long long bsPQK = (long long)SAUG * 2048;
    const long long bsO   = (long long)S_ * BR_DIM;
    const int KP32 = 1024;
    const int KP64 = 1088;
    dim3 ablock(256);
    dim3 agrid4(S_ / 128, NH, B_), agrid8(S_ / 256, NH, 2 * B_);
    dim3 tgrid32(16, NH, B_), tgrid64(17, NH, 2 * B_);

    // ---- MHA 1 (spatial) ----
    gemm<0>(stream, CNN_B, W_SA_QKV, F(4), nullptr, QKV, M4, 3 * CNN_DIM, CNN_DIM);
    transpose_v<32, false><<<tgrid32, 256, 0, stream>>>(QKV + 2 * CNN_DIM, VT32, nullptr, S_, 3 * CNN_DIM, bsQKV, KP32);
    attn10<32, false, 2><<<agrid4, ablock, 0, stream>>>(QKV, QKV + CNN_DIM, VT32, nullptr, ATT,
        S_, 3 * CNN_DIM, 3 * CNN_DIM, CNN_DIM, bsQKV, bsQKV, bsATT, KP32, sc32);
    gemm<2>(stream, ATT, W_SA_O, F(6), F(2), CNN1, M4, CNN_DIM, CNN_DIM);

    // ---- MHA 2 (temporal) ----
    gemm<0>(stream, CNN1, W_TA_QKV, F(8), nullptr, QKV, M4, 3 * CNN_DIM, CNN_DIM);
    transpose_v<32, false><<<tgrid32, 256, 0, stream>>>(QKV + 2 * CNN_DIM, VT32, nullptr, S_, 3 * CNN_DIM, bsQKV, KP32);
    attn10<32, false, 2><<<agrid4, ablock, 0, stream>>>(QKV, QKV + CNN_DIM, VT32, nullptr, ATT,
        S_, 3 * CNN_DIM, 3 * CNN_DIM, CNN_DIM, bsQKV, bsQKV, bsATT, KP32, sc32);
    gemm<1>(stream, ATT, W_TA_O, F(10), CNN1, CNN2, M4, CNN_DIM, CNN_DIM);

    // ---- bridges to BR_DIM (Linear -> GELU -> LN) ----
    gemm<0>(stream, LLM_B, W_L2B, F(16), nullptr, X8, M4, BR_DIM, LLM_DIM);
    ln_kernel<true, false, false><<<M4, 256, 0, stream>>>(X8, nullptr, F(17), F(18), AUGL,
        BR_DIM, S_, 0, 0, bsAUG, BR_DIM);
    gemm<0>(stream, CNN2, W_C2B, F(12), nullptr, X8, M4, BR_DIM, CNN_DIM);
    ln_kernel<true, false, false><<<M4, 256, 0, stream>>>(X8, nullptr, F(13), F(14), AUGC,
        BR_DIM, S_, 0, 0, bsAUG, BR_DIM);
    fill_phys_kernel<<<12, 256, 0, stream>>>(F(27), F(28), F(29), AUGC, AUGL);

    // ---- merged phys projections: fused Q|K (N=2048) + V, over [AUGC;AUGL] (M=8216) ----
    gemm<0>(stream, AUGC, W_PQ, BIAS2, nullptr, PQK_ALL, 2 * MA, 2048, BR_DIM);
    gemm<0>(stream, AUGC, W_PV, F(24), nullptr, PV_ALL, 2 * MA, BR_DIM, BR_DIM);
    transpose_v<64, true><<<tgrid64, 256, 0, stream>>>(PV_ALL, VTA, VTB, SAUG, BR_DIM, bsAUG, KP64);

    // ---- merged phys attention, QG=4 + dbuf (z<4: cnn-q x llm-kv; z>=4: llm-q x cnn-kv) ----
    attn10<64, true, 4><<<agrid8, ablock, 0, stream>>>(PQK_ALL, PQK_ALL + 1024, VTA, VTB, OB_ALL,
        SAUG, 2048, 2048, BR_DIM, bsPQK, bsPQK, bsO, KP64, sc64);

    // ---- merged PO projection + residual LN ----
    gemm<0>(stream, OB_ALL, W_PO, F(26), nullptr, X8_ALL, 2 * M4, BR_DIM, BR_DIM);
    ln_kernel<false, true, false><<<2 * M4, 256, 0, stream>>>(X8_ALL, AUGC, F(30), F(31), CATT_ALL,
        BR_DIM, S_, bsAUG, BR_DIM, bsO, BR_DIM);

    // ---- final bridges (f32 to d_out) ----
    gemm<0>(stream, CATT_ALL, W_C2L, F(33), nullptr, X6, M4, LLM_DIM, BR_DIM);
    ln_kernel<true, false, true><<<M4, 256, 0, stream>>>(X6, nullptr, F(34), F(35),
        (void*)(outp + 2097152), LLM_DIM, S_, 0, 0, (long long)S_ * LLM_DIM, LLM_DIM);
    gemm<0>(stream, CATT_ALL + (size_t)M4 * BR_DIM, W_L2C, F(37), nullptr, X4, M4, CNN_DIM, BR_DIM);
    ln_kernel<true, false, true><<<M4, 256, 0, stream>>>(X4, nullptr, F(38), F(39),
        (void*)outp, CNN_DIM, S_, 0, 0, (long long)S_ * CNN_DIM, CNN_DIM);
}